// Round 1
// 8878.741 us; speedup vs baseline: 3.0446x; 3.0446x over previous
//
#include <hip/hip_runtime.h>
#include <hip/hip_bf16.h>
#include <math.h>

// TransformerBlock B=4 S=2048 H=16 dh=64 D=1024 FF=2048.
// ROUND 8: replace one-thread-per-element naive GEMM with 128x128x16 LDS-tiled
// fp32 GEMM (8x8 register microtile per thread, 2x2 split of 4x4 for broadcast-
// friendly ds_read_b128). Attention / LN / qkv_post unchanged (all-fp32 pipeline,
// fp32 output). Inputs remain dtype-polymorphic via detect_k (fp32 vs bf16).
// Buffers: qkv fp32 in ws[0,100.6M) with in-place rope; V fp32 [100.6M,134.2M);
// att staged in d_out; x/h overlay dead qkv region. WS_NEED=135MB.

typedef __bf16 bf16_t;

#define B_  4
#define S_  2048
#define H_  16
#define DH_ 64
#define D_  1024
#define FF_ 2048
#define M_  (B_ * S_)   // 8192

__device__ __forceinline__ float ldx(const void* p, int i, int f) {
    return f ? ((const float*)p)[i] : (float)((const bf16_t*)p)[i];
}

// ---- detect input dtype from Q's bit patterns; flag[0]=1 iff fp32; flag[1]=1 ----
__global__ void detect_k(const unsigned short* q, int n, int* flag) {
    const int tid = threadIdx.x;           // single block of 256
    float cnt = 0.f;
    for (int i = tid; i < n; i += 256) {
        const int e = (q[i] >> 7) & 0xFF;  // bf16 exponent field
        if (e >= 134) cnt += 1.f;          // impossible for N(0,1) bf16
    }
    __shared__ float red[256];
    red[tid] = cnt;
    __syncthreads();
    for (int s = 128; s > 0; s >>= 1) {
        if (tid < s) red[tid] += red[tid + s];
        __syncthreads();
    }
    if (tid == 0) { flag[0] = (red[0] > 0.5f) ? 1 : 0; flag[1] = 1; }
}

// ---------------- rope tables ----------------
__global__ void rope_tables_k(float* __restrict__ ct, float* __restrict__ st,
                              float* __restrict__ sct) {
    const int s = blockIdx.x, i = threadIdx.x;   // grid S_, block 32
    const float inv_freq = powf(10000.f, -(float)i / 32.f);
    const float f = (float)s * inv_freq;
    ct[s * 32 + i] = cosf(f);
    st[s * 32 + i] = sinf(f);
    const float base = (2.f * (float)i + 25.6f) / 89.6f;
    const float pw = ((float)s - 1024.f) / 512.f;
    sct[s * 32 + i] = powf(base, pw);
}

// ------------- tiled fp32 GEMM: C[M,N] = A @ Bw + bias (+silu) (+resid) -------------
// 128x128 tile per 256-thread block, BK=16. Each thread: 8x8 = 2x2 blocks of 4x4.
// rows: bm + i*64 + ty*4 + r ; cols: bn + j*64 + tx*4 + c  (tx=tid&15, ty=tid>>4).
// LDS: As transposed [BK][BM+4] (pad -> <=2-way on write, b128 broadcast on read);
//      Bs [BK][BN] (write conflict-free, read 2-way b128 = free).
// Requires M%128==0, N%128==0, K%16==0 (true for all call sites).
template <int ACT, bool RES>
__global__ __launch_bounds__(256)
void tile_gemm_k(const void* __restrict__ A, const int* __restrict__ fA,
                 const void* __restrict__ Bw, const int* __restrict__ fB,
                 const void* __restrict__ bias, const int* __restrict__ fbias,
                 const float* __restrict__ resid, float* __restrict__ C,
                 int M, int N, int K) {
    constexpr int BM = 128, BN = 128, BK = 16;
    __shared__ float As[BK][BM + 4];
    __shared__ float Bs[BK][BN];
    const int tid = threadIdx.x;
    const int tx = tid & 15, ty = tid >> 4;
    const int bm = blockIdx.y * BM, bn = blockIdx.x * BN;
    const int fa = fA[0], fb = fB[0], fc = fbias[0];
    (void)M;

    float acc[2][2][4][4];
#pragma unroll
    for (int i = 0; i < 2; ++i)
#pragma unroll
        for (int j = 0; j < 2; ++j)
#pragma unroll
            for (int r = 0; r < 4; ++r)
#pragma unroll
                for (int c = 0; c < 4; ++c) acc[i][j][r][c] = 0.f;

    for (int k0 = 0; k0 < K; k0 += BK) {
        __syncthreads();   // protect LDS from previous iteration's readers
        // A tile: 128 rows x 16 cols, store transposed As[col][row]
#pragma unroll
        for (int i = 0; i < 8; ++i) {
            const int e = i * 256 + tid;
            const int r = e >> 4, c = e & 15;        // r:0..127  c:0..15
            As[c][r] = ldx(A, (bm + r) * K + k0 + c, fa);
        }
        // B tile: 16 rows x 128 cols
#pragma unroll
        for (int i = 0; i < 8; ++i) {
            const int e = i * 256 + tid;
            const int r = e >> 7, c = e & 127;       // r:0..15  c:0..127
            Bs[r][c] = ldx(Bw, (k0 + r) * N + bn + c, fb);
        }
        __syncthreads();
#pragma unroll
        for (int kk = 0; kk < BK; ++kk) {
            float a[2][4], b[2][4];
#pragma unroll
            for (int r = 0; r < 4; ++r) {
                a[0][r] = As[kk][ty * 4 + r];
                a[1][r] = As[kk][ty * 4 + 64 + r];
            }
#pragma unroll
            for (int c = 0; c < 4; ++c) {
                b[0][c] = Bs[kk][tx * 4 + c];
                b[1][c] = Bs[kk][tx * 4 + 64 + c];
            }
#pragma unroll
            for (int i = 0; i < 2; ++i)
#pragma unroll
                for (int r = 0; r < 4; ++r)
#pragma unroll
                    for (int j = 0; j < 2; ++j)
#pragma unroll
                        for (int c = 0; c < 4; ++c)
                            acc[i][j][r][c] = fmaf(a[i][r], b[j][c], acc[i][j][r][c]);
        }
    }

    // epilogue: bias (+silu) (+resid), float4 stores (col0 16B-aligned)
#pragma unroll
    for (int i = 0; i < 2; ++i) {
#pragma unroll
        for (int r = 0; r < 4; ++r) {
            const int row = bm + i * 64 + ty * 4 + r;
#pragma unroll
            for (int j = 0; j < 2; ++j) {
                const int col0 = bn + j * 64 + tx * 4;
                float4 v;
                float* vp = &v.x;
#pragma unroll
                for (int c = 0; c < 4; ++c) {
                    float t = acc[i][j][r][c] + ldx(bias, col0 + c, fc);
                    if constexpr (ACT == 1) t = t / (1.f + expf(-t));
                    if constexpr (RES) t += resid[(size_t)row * N + col0 + c];
                    vp[c] = t;
                }
                *(float4*)(C + (size_t)row * N + col0) = v;
            }
        }
    }
}

// ------------- qkv post: in-place l2norm+scale+rope on q,k; v -> Vr -------------
__global__ __launch_bounds__(256)
void qkv_post_k(float* __restrict__ qkv,
                const void* __restrict__ qsc, const void* __restrict__ ksc,
                const int* __restrict__ flag,
                const float* __restrict__ ct, const float* __restrict__ st,
                const float* __restrict__ sct, float* __restrict__ Vr) {
    const int id = blockIdx.x * 256 + threadIdx.x;   // [0, M_*H_)
    if (id >= M_ * H_) return;
    const int f = flag[0];
    const int bs = id >> 4, h = id & 15;
    const int s = bs & (S_ - 1), b = bs >> 11;
    float* row = qkv + (size_t)bs * (3 * D_) + h * 192;
    const size_t vb = ((size_t)(b * H_ + h) * S_ + s) * DH_;

    float q[DH_];
    // ---- q ----
    float n2 = 0.f;
#pragma unroll
    for (int d = 0; d < DH_; ++d) { q[d] = row[d]; n2 += q[d] * q[d]; }
    float inv = 1.f / fmaxf(sqrtf(n2), 1e-12f);
#pragma unroll
    for (int d = 0; d < DH_; ++d) q[d] *= inv * ldx(qsc, d, f);
#pragma unroll
    for (int d = 0; d < 32; ++d) {
        const float c = ct[s * 32 + d], sn = st[s * 32 + d], sc = sct[s * 32 + d];
        const float a = q[d], bb = q[d + 32];
        q[d]      = (a * c - bb * sn) * sc;
        q[d + 32] = (bb * c + a * sn) * sc;
    }
#pragma unroll
    for (int d = 0; d < DH_; ++d) row[d] = q[d];
    // ---- k ----
    n2 = 0.f;
#pragma unroll
    for (int d = 0; d < DH_; ++d) { q[d] = row[64 + d]; n2 += q[d] * q[d]; }
    inv = 1.f / fmaxf(sqrtf(n2), 1e-12f);
#pragma unroll
    for (int d = 0; d < DH_; ++d) q[d] *= inv * ldx(ksc, d, f);
#pragma unroll
    for (int d = 0; d < 32; ++d) {
        const float c = ct[s * 32 + d], sn = st[s * 32 + d], isc = 1.f / sct[s * 32 + d];
        const float a = q[d], bb = q[d + 32];
        q[d]      = (a * c - bb * sn) * isc;
        q[d + 32] = (bb * c + a * sn) * isc;
    }
#pragma unroll
    for (int d = 0; d < DH_; ++d) row[64 + d] = q[d];
    // ---- v ----
#pragma unroll
    for (int d = 0; d < DH_; ++d) Vr[vb + d] = row[128 + d];
}

// ------------- naive attention: one thread per (b,h,sq), two-pass, fp32 -------------
__global__ __launch_bounds__(256)
void attn_naive_k(const float* __restrict__ qkv, const float* __restrict__ Vr,
                  float* __restrict__ att) {
    const int id = blockIdx.x * 256 + threadIdx.x;   // [0, B_*H_*S_)
    if (id >= B_ * H_ * S_) return;
    const int hb = id >> 11, sq = id & (S_ - 1);
    const int b = hb >> 4, h = hb & 15;

    float q[DH_];
    const float* qrow = qkv + (size_t)(b * S_ + sq) * (3 * D_) + h * 192;
#pragma unroll
    for (int d = 0; d < DH_; ++d) q[d] = qrow[d];
    const float* Vb = Vr + (size_t)hb * S_ * DH_;

    float mx = -1e30f;
    for (int j = 0; j < S_; ++j) {
        const float* kj = qkv + (size_t)(b * S_ + j) * (3 * D_) + h * 192 + 64;
        float dot = 0.f;
#pragma unroll
        for (int d = 0; d < DH_; ++d) dot += q[d] * kj[d];
        mx = fmaxf(mx, dot * 0.125f);
    }
    float o[DH_];
#pragma unroll
    for (int d = 0; d < DH_; ++d) o[d] = 0.f;
    float sum = 0.f;
    for (int j = 0; j < S_; ++j) {
        const float* kj = qkv + (size_t)(b * S_ + j) * (3 * D_) + h * 192 + 64;
        float dot = 0.f;
#pragma unroll
        for (int d = 0; d < DH_; ++d) dot += q[d] * kj[d];
        const float p = expf(fminf(dot * 0.125f - mx, 0.f));
        sum += p;
        const float* vj = Vb + (size_t)j * DH_;
#pragma unroll
        for (int d = 0; d < DH_; ++d) o[d] += p * vj[d];
    }
    const float isum = 1.f / fmaxf(sum, 1e-20f);
    float* orow = att + (size_t)(b * S_ + sq) * D_ + h * DH_;
#pragma unroll
    for (int d = 0; d < DH_; ++d) orow[d] = o[d] * isum;
}

// ------------- LayerNorm over D=1024, fp32 in/out -------------
__global__ __launch_bounds__(256)
void layernorm_k(const float* __restrict__ in, const void* __restrict__ g,
                 const void* __restrict__ be, const int* __restrict__ flag,
                 float* __restrict__ xo) {
    const int row = blockIdx.x, tid = threadIdx.x;
    const int lane = tid & 63, wave = tid >> 6;
    const int f = flag[0];
    const float* r = in + (size_t)row * D_;
    float v[4], s = 0.f, ss = 0.f;
#pragma unroll
    for (int i = 0; i < 4; ++i) {
        v[i] = r[tid + i * 256];
        s += v[i]; ss += v[i] * v[i];
    }
#pragma unroll
    for (int msk = 1; msk < 64; msk <<= 1) { s += __shfl_xor(s, msk); ss += __shfl_xor(ss, msk); }
    __shared__ float rs[4], rss[4];
    if (lane == 0) { rs[wave] = s; rss[wave] = ss; }
    __syncthreads();
    s = rs[0] + rs[1] + rs[2] + rs[3];
    ss = rss[0] + rss[1] + rss[2] + rss[3];
    const float mu = s * (1.f / (float)D_);
    const float var = fmaxf(ss * (1.f / (float)D_) - mu * mu, 0.f);
    const float inv = rsqrtf(var + 1e-5f);
    float* xr = xo + (size_t)row * D_;
#pragma unroll
    for (int i = 0; i < 4; ++i) {
        const int c = tid + i * 256;
        xr[c] = (v[i] - mu) * inv * ldx(g, c, f) + ldx(be, c, f);
    }
}

__global__ void host_marker_k(int code, float* __restrict__ out) {
    if (code != 0) out[0] = 1e10f * (float)(1 + code);
}

extern "C" void kernel_launch(void* const* d_in, const int* in_sizes, int n_in,
                              void* d_out, int out_size, void* d_ws, size_t ws_size,
                              hipStream_t stream) {
    (void)out_size;
    const void* Q    = d_in[0];
    const void* Wqkv = d_in[3];
    const void* bqkv = d_in[4];
    const void* qsc  = d_in[5];
    const void* ksc  = d_in[6];
    const void* ln_g = d_in[7];
    const void* ln_b = d_in[8];
    const void* W1   = d_in[9];
    const void* b1   = d_in[10];
    const void* W2   = d_in[11];
    const void* b2   = d_in[12];

    // ws layout (bytes): qkv fp32 [0,100663296) -> later xbuf [0,33554432) +
    // hbuf [33554432,100663296); Vr fp32 [100663296,134217728); rope+flag tail.
    constexpr size_t OFF_QKV  = 0;
    constexpr size_t OFF_X    = 0;
    constexpr size_t OFF_HB   = 33554432;
    constexpr size_t OFF_VR   = 100663296;
    constexpr size_t OFF_RC   = OFF_VR + 33554432;   // 134217728
    constexpr size_t OFF_RS   = OFF_RC + 262144;
    constexpr size_t OFF_RSC  = OFF_RS + 262144;
    constexpr size_t OFF_FLAG = OFF_RSC + 262144;    // 135004160
    constexpr size_t WS_NEED  = OFF_FLAG + 64;

    float* out = (float*)d_out;                      // FP32 output (and att scratch)
    char* ws = (char*)d_ws;
    float* qkv  = (float*)(ws + OFF_QKV);
    float* xbuf = (float*)(ws + OFF_X);
    float* hbuf = (float*)(ws + OFF_HB);
    float* Vr   = (float*)(ws + OFF_VR);
    float* rc   = (float*)(ws + OFF_RC);
    float* rsn  = (float*)(ws + OFF_RS);
    float* rsc  = (float*)(ws + OFF_RSC);
    int*   flag = (int*)(ws + OFF_FLAG);   // flag[0]=input dtype (1=fp32), flag[1]=1

    int err_stage = 0;
    (void)hipGetLastError();
    #define LCHK(stage) do { if (hipGetLastError() != hipSuccess && err_stage == 0) err_stage = (stage); } while (0)

    if (n_in != 13) err_stage = 90;
    else if (in_sizes[0] != 8388608 || in_sizes[3] != 3145728 || in_sizes[4] != 3072 ||
             in_sizes[5] != 64 || in_sizes[7] != 1024 || in_sizes[9] != 2097152 ||
             in_sizes[10] != 2048 || in_sizes[11] != 2097152 || in_sizes[12] != 1024)
        err_stage = 91;
    else if (ws_size < WS_NEED) err_stage = 92;
    if (err_stage != 0) {
        host_marker_k<<<1, 1, 0, stream>>>(err_stage, out);
        return;
    }

    detect_k<<<1, 256, 0, stream>>>((const unsigned short*)Q, 65536, flag);        LCHK(1);
    rope_tables_k<<<S_, 32, 0, stream>>>(rc, rsn, rsc);                            LCHK(2);
    // qkv = Q @ Wqkv + bqkv  (fp32, tiled)
    {
        dim3 g(3 * D_ / 128, M_ / 128);
        tile_gemm_k<0, false><<<g, 256, 0, stream>>>(
            Q, flag, Wqkv, flag, bqkv, flag, nullptr, qkv, M_, 3 * D_, D_);        LCHK(3);
    }
    // in-place l2norm + scale + rope on q,k; v -> Vr
    qkv_post_k<<<(M_ * H_) / 256, 256, 0, stream>>>(
        qkv, qsc, ksc, flag, rc, rsn, rsc, Vr);                                    LCHK(4);
    // attention -> att staged in d_out (fp32)
    attn_naive_k<<<(B_ * H_ * S_) / 256, 256, 0, stream>>>(qkv, Vr, out);          LCHK(5);
    // LayerNorm(att) -> xbuf (qkv region now dead)
    layernorm_k<<<M_, 256, 0, stream>>>(out, ln_g, ln_b, flag, xbuf);              LCHK(6);
    // h = silu(x @ W1 + b1)   (fp32 ws inputs use flag[1]=1)
    {
        dim3 g(FF_ / 128, M_ / 128);
        tile_gemm_k<1, false><<<g, 256, 0, stream>>>(
            xbuf, flag + 1, W1, flag, b1, flag, nullptr, hbuf, M_, FF_, D_);       LCHK(7);
    }
    // out = x + h @ W2 + b2  (overwrites att scratch)
    {
        dim3 g(D_ / 128, M_ / 128);
        tile_gemm_k<0, true><<<g, 256, 0, stream>>>(
            hbuf, flag + 1, W2, flag, b2, flag, xbuf, out, M_, D_, FF_);           LCHK(8);
    }
    host_marker_k<<<1, 1, 0, stream>>>(err_stage, out);
    #undef LCHK
}

// Round 2
// 4261.415 us; speedup vs baseline: 6.3434x; 2.0835x over previous
//
#include <hip/hip_runtime.h>
#include <hip/hip_bf16.h>
#include <math.h>

// TransformerBlock B=4 S=2048 H=16 dh=64 D=1024 FF=2048.
// ROUND 9: flash-style fp32 attention (no-max-softmax, LDS K/V tiles, broadcast
// ds_read_b128, paired-j ILP). Safe since |logit| <= 0.125*12.25^2 ~ 18.8 by
// Cauchy-Schwarz (l2-normalized q,k x bounded rope scales). Dropped Vr copy.
// GEMMs remain 128x128x16 fp32 LDS-tiled from round 8. All-fp32 pipeline.
// Buffers: qkv fp32 ws[0,100.6M) in-place rope; att staged in d_out;
// x/h overlay dead qkv region. WS_NEED unchanged (Vr region now unused).

typedef __bf16 bf16_t;

#define B_  4
#define S_  2048
#define H_  16
#define DH_ 64
#define D_  1024
#define FF_ 2048
#define M_  (B_ * S_)   // 8192

__device__ __forceinline__ float ldx(const void* p, int i, int f) {
    return f ? ((const float*)p)[i] : (float)((const bf16_t*)p)[i];
}

// ---- detect input dtype from Q's bit patterns; flag[0]=1 iff fp32; flag[1]=1 ----
__global__ void detect_k(const unsigned short* q, int n, int* flag) {
    const int tid = threadIdx.x;           // single block of 256
    float cnt = 0.f;
    for (int i = tid; i < n; i += 256) {
        const int e = (q[i] >> 7) & 0xFF;  // bf16 exponent field
        if (e >= 134) cnt += 1.f;          // impossible for N(0,1) bf16
    }
    __shared__ float red[256];
    red[tid] = cnt;
    __syncthreads();
    for (int s = 128; s > 0; s >>= 1) {
        if (tid < s) red[tid] += red[tid + s];
        __syncthreads();
    }
    if (tid == 0) { flag[0] = (red[0] > 0.5f) ? 1 : 0; flag[1] = 1; }
}

// ---------------- rope tables ----------------
__global__ void rope_tables_k(float* __restrict__ ct, float* __restrict__ st,
                              float* __restrict__ sct) {
    const int s = blockIdx.x, i = threadIdx.x;   // grid S_, block 32
    const float inv_freq = powf(10000.f, -(float)i / 32.f);
    const float f = (float)s * inv_freq;
    ct[s * 32 + i] = cosf(f);
    st[s * 32 + i] = sinf(f);
    const float base = (2.f * (float)i + 25.6f) / 89.6f;
    const float pw = ((float)s - 1024.f) / 512.f;
    sct[s * 32 + i] = powf(base, pw);
}

// ------------- tiled fp32 GEMM: C[M,N] = A @ Bw + bias (+silu) (+resid) -------------
// 128x128 tile per 256-thread block, BK=16. Each thread: 8x8 = 2x2 blocks of 4x4.
template <int ACT, bool RES>
__global__ __launch_bounds__(256)
void tile_gemm_k(const void* __restrict__ A, const int* __restrict__ fA,
                 const void* __restrict__ Bw, const int* __restrict__ fB,
                 const void* __restrict__ bias, const int* __restrict__ fbias,
                 const float* __restrict__ resid, float* __restrict__ C,
                 int M, int N, int K) {
    constexpr int BM = 128, BN = 128, BK = 16;
    __shared__ float As[BK][BM + 4];
    __shared__ float Bs[BK][BN];
    const int tid = threadIdx.x;
    const int tx = tid & 15, ty = tid >> 4;
    const int bm = blockIdx.y * BM, bn = blockIdx.x * BN;
    const int fa = fA[0], fb = fB[0], fc = fbias[0];
    (void)M;

    float acc[2][2][4][4];
#pragma unroll
    for (int i = 0; i < 2; ++i)
#pragma unroll
        for (int j = 0; j < 2; ++j)
#pragma unroll
            for (int r = 0; r < 4; ++r)
#pragma unroll
                for (int c = 0; c < 4; ++c) acc[i][j][r][c] = 0.f;

    for (int k0 = 0; k0 < K; k0 += BK) {
        __syncthreads();   // protect LDS from previous iteration's readers
        // A tile: 128 rows x 16 cols, store transposed As[col][row]
#pragma unroll
        for (int i = 0; i < 8; ++i) {
            const int e = i * 256 + tid;
            const int r = e >> 4, c = e & 15;        // r:0..127  c:0..15
            As[c][r] = ldx(A, (bm + r) * K + k0 + c, fa);
        }
        // B tile: 16 rows x 128 cols
#pragma unroll
        for (int i = 0; i < 8; ++i) {
            const int e = i * 256 + tid;
            const int r = e >> 7, c = e & 127;       // r:0..15  c:0..127
            Bs[r][c] = ldx(Bw, (k0 + r) * N + bn + c, fb);
        }
        __syncthreads();
#pragma unroll
        for (int kk = 0; kk < BK; ++kk) {
            float a[2][4], b[2][4];
#pragma unroll
            for (int r = 0; r < 4; ++r) {
                a[0][r] = As[kk][ty * 4 + r];
                a[1][r] = As[kk][ty * 4 + 64 + r];
            }
#pragma unroll
            for (int c = 0; c < 4; ++c) {
                b[0][c] = Bs[kk][tx * 4 + c];
                b[1][c] = Bs[kk][tx * 4 + 64 + c];
            }
#pragma unroll
            for (int i = 0; i < 2; ++i)
#pragma unroll
                for (int r = 0; r < 4; ++r)
#pragma unroll
                    for (int j = 0; j < 2; ++j)
#pragma unroll
                        for (int c = 0; c < 4; ++c)
                            acc[i][j][r][c] = fmaf(a[i][r], b[j][c], acc[i][j][r][c]);
        }
    }

    // epilogue: bias (+silu) (+resid), float4 stores
#pragma unroll
    for (int i = 0; i < 2; ++i) {
#pragma unroll
        for (int r = 0; r < 4; ++r) {
            const int row = bm + i * 64 + ty * 4 + r;
#pragma unroll
            for (int j = 0; j < 2; ++j) {
                const int col0 = bn + j * 64 + tx * 4;
                float4 v;
                float* vp = &v.x;
#pragma unroll
                for (int c = 0; c < 4; ++c) {
                    float t = acc[i][j][r][c] + ldx(bias, col0 + c, fc);
                    if constexpr (ACT == 1) t = t / (1.f + expf(-t));
                    if constexpr (RES) t += resid[(size_t)row * N + col0 + c];
                    vp[c] = t;
                }
                *(float4*)(C + (size_t)row * N + col0) = v;
            }
        }
    }
}

// ------------- qkv post: in-place l2norm+scale+rope on q,k -------------
__global__ __launch_bounds__(256)
void qkv_post_k(float* __restrict__ qkv,
                const void* __restrict__ qsc, const void* __restrict__ ksc,
                const int* __restrict__ flag,
                const float* __restrict__ ct, const float* __restrict__ st,
                const float* __restrict__ sct) {
    const int id = blockIdx.x * 256 + threadIdx.x;   // [0, M_*H_)
    if (id >= M_ * H_) return;
    const int f = flag[0];
    const int bs = id >> 4, h = id & 15;
    const int s = bs & (S_ - 1);
    float* row = qkv + (size_t)bs * (3 * D_) + h * 192;

    float q[DH_];
    // ---- q ----
    float n2 = 0.f;
#pragma unroll
    for (int d = 0; d < DH_; ++d) { q[d] = row[d]; n2 += q[d] * q[d]; }
    float inv = 1.f / fmaxf(sqrtf(n2), 1e-12f);
#pragma unroll
    for (int d = 0; d < DH_; ++d) q[d] *= inv * ldx(qsc, d, f);
#pragma unroll
    for (int d = 0; d < 32; ++d) {
        const float c = ct[s * 32 + d], sn = st[s * 32 + d], sc = sct[s * 32 + d];
        const float a = q[d], bb = q[d + 32];
        q[d]      = (a * c - bb * sn) * sc;
        q[d + 32] = (bb * c + a * sn) * sc;
    }
#pragma unroll
    for (int d = 0; d < DH_; ++d) row[d] = q[d];
    // ---- k ----
    n2 = 0.f;
#pragma unroll
    for (int d = 0; d < DH_; ++d) { q[d] = row[64 + d]; n2 += q[d] * q[d]; }
    inv = 1.f / fmaxf(sqrtf(n2), 1e-12f);
#pragma unroll
    for (int d = 0; d < DH_; ++d) q[d] *= inv * ldx(ksc, d, f);
#pragma unroll
    for (int d = 0; d < 32; ++d) {
        const float c = ct[s * 32 + d], sn = st[s * 32 + d], isc = 1.f / sct[s * 32 + d];
        const float a = q[d], bb = q[d + 32];
        q[d]      = (a * c - bb * sn) * isc;
        q[d + 32] = (bb * c + a * sn) * isc;
    }
#pragma unroll
    for (int d = 0; d < DH_; ++d) row[64 + d] = q[d];
}

// ------------- flash-style fp32 attention -------------
// Block = 256 threads = 256 consecutive q-rows of one (b,h). K/V staged in LDS
// 64 rows at a time; all threads walk j together -> LDS reads are wave-uniform
// broadcasts (conflict-free). No max subtraction: |logit| <= 18.8 guaranteed
// (l2-normalized q,k x rope scale bounds), exp<=1.4e8, sum<=3e11 -- fp32 safe.
__global__ __launch_bounds__(256)
void attn_flash_k(const float* __restrict__ qkv, float* __restrict__ att) {
    __shared__ float4 Ks[64][16];
    __shared__ float4 Vs[64][16];
    const int tid = threadIdx.x;
    const int qt = blockIdx.x & 7;
    const int h  = (blockIdx.x >> 3) & 15;
    const int b  = blockIdx.x >> 7;
    const int sq = qt * 256 + tid;

    const float* qrow = qkv + (size_t)(b * S_ + sq) * (3 * D_) + h * 192;
    float4 q4[16];
#pragma unroll
    for (int i = 0; i < 16; ++i) {
        q4[i] = ((const float4*)qrow)[i];
        q4[i].x *= 0.125f; q4[i].y *= 0.125f; q4[i].z *= 0.125f; q4[i].w *= 0.125f;
    }
    float4 o4[16];
#pragma unroll
    for (int i = 0; i < 16; ++i) o4[i] = make_float4(0.f, 0.f, 0.f, 0.f);
    float sum = 0.f;

    const int lr = tid >> 4, lc = tid & 15;
    for (int j0 = 0; j0 < S_; j0 += 64) {
        __syncthreads();   // previous tile's readers done
#pragma unroll
        for (int i = 0; i < 4; ++i) {
            const int r = lr + i * 16;
            const float* krow = qkv + (size_t)(b * S_ + j0 + r) * (3 * D_) + h * 192 + 64;
            Ks[r][lc] = ((const float4*)krow)[lc];
            Vs[r][lc] = ((const float4*)(krow + 64))[lc];
        }
        __syncthreads();
        for (int j = 0; j < 64; j += 2) {
            float4 a0 = make_float4(0.f, 0.f, 0.f, 0.f);
            float4 a1 = make_float4(0.f, 0.f, 0.f, 0.f);
#pragma unroll
            for (int dd = 0; dd < 16; ++dd) {
                const float4 qq = q4[dd];
                const float4 k0 = Ks[j][dd];
                const float4 k1 = Ks[j + 1][dd];
                a0.x = fmaf(qq.x, k0.x, a0.x); a0.y = fmaf(qq.y, k0.y, a0.y);
                a0.z = fmaf(qq.z, k0.z, a0.z); a0.w = fmaf(qq.w, k0.w, a0.w);
                a1.x = fmaf(qq.x, k1.x, a1.x); a1.y = fmaf(qq.y, k1.y, a1.y);
                a1.z = fmaf(qq.z, k1.z, a1.z); a1.w = fmaf(qq.w, k1.w, a1.w);
            }
            const float p0 = __expf((a0.x + a0.y) + (a0.z + a0.w));
            const float p1 = __expf((a1.x + a1.y) + (a1.z + a1.w));
            sum += p0 + p1;
#pragma unroll
            for (int dd = 0; dd < 16; ++dd) {
                const float4 v0 = Vs[j][dd];
                const float4 v1 = Vs[j + 1][dd];
                o4[dd].x = fmaf(p1, v1.x, fmaf(p0, v0.x, o4[dd].x));
                o4[dd].y = fmaf(p1, v1.y, fmaf(p0, v0.y, o4[dd].y));
                o4[dd].z = fmaf(p1, v1.z, fmaf(p0, v0.z, o4[dd].z));
                o4[dd].w = fmaf(p1, v1.w, fmaf(p0, v0.w, o4[dd].w));
            }
        }
    }
    const float isum = 1.f / sum;
    float4* orow = (float4*)(att + (size_t)(b * S_ + sq) * D_ + h * DH_);
#pragma unroll
    for (int i = 0; i < 16; ++i) {
        float4 o = o4[i];
        o.x *= isum; o.y *= isum; o.z *= isum; o.w *= isum;
        orow[i] = o;
    }
}

// ------------- LayerNorm over D=1024, fp32 in/out -------------
__global__ __launch_bounds__(256)
void layernorm_k(const float* __restrict__ in, const void* __restrict__ g,
                 const void* __restrict__ be, const int* __restrict__ flag,
                 float* __restrict__ xo) {
    const int row = blockIdx.x, tid = threadIdx.x;
    const int lane = tid & 63, wave = tid >> 6;
    const int f = flag[0];
    const float* r = in + (size_t)row * D_;
    float v[4], s = 0.f, ss = 0.f;
#pragma unroll
    for (int i = 0; i < 4; ++i) {
        v[i] = r[tid + i * 256];
        s += v[i]; ss += v[i] * v[i];
    }
#pragma unroll
    for (int msk = 1; msk < 64; msk <<= 1) { s += __shfl_xor(s, msk); ss += __shfl_xor(ss, msk); }
    __shared__ float rs[4], rss[4];
    if (lane == 0) { rs[wave] = s; rss[wave] = ss; }
    __syncthreads();
    s = rs[0] + rs[1] + rs[2] + rs[3];
    ss = rss[0] + rss[1] + rss[2] + rss[3];
    const float mu = s * (1.f / (float)D_);
    const float var = fmaxf(ss * (1.f / (float)D_) - mu * mu, 0.f);
    const float inv = rsqrtf(var + 1e-5f);
    float* xr = xo + (size_t)row * D_;
#pragma unroll
    for (int i = 0; i < 4; ++i) {
        const int c = tid + i * 256;
        xr[c] = (v[i] - mu) * inv * ldx(g, c, f) + ldx(be, c, f);
    }
}

__global__ void host_marker_k(int code, float* __restrict__ out) {
    if (code != 0) out[0] = 1e10f * (float)(1 + code);
}

extern "C" void kernel_launch(void* const* d_in, const int* in_sizes, int n_in,
                              void* d_out, int out_size, void* d_ws, size_t ws_size,
                              hipStream_t stream) {
    (void)out_size;
    const void* Q    = d_in[0];
    const void* Wqkv = d_in[3];
    const void* bqkv = d_in[4];
    const void* qsc  = d_in[5];
    const void* ksc  = d_in[6];
    const void* ln_g = d_in[7];
    const void* ln_b = d_in[8];
    const void* W1   = d_in[9];
    const void* b1   = d_in[10];
    const void* W2   = d_in[11];
    const void* b2   = d_in[12];

    // ws layout (bytes): qkv fp32 [0,100663296) -> later xbuf [0,33554432) +
    // hbuf [33554432,100663296); [100663296,134217728) unused; rope+flag tail.
    constexpr size_t OFF_QKV  = 0;
    constexpr size_t OFF_X    = 0;
    constexpr size_t OFF_HB   = 33554432;
    constexpr size_t OFF_VR   = 100663296;           // unused (kept for layout)
    constexpr size_t OFF_RC   = OFF_VR + 33554432;   // 134217728
    constexpr size_t OFF_RS   = OFF_RC + 262144;
    constexpr size_t OFF_RSC  = OFF_RS + 262144;
    constexpr size_t OFF_FLAG = OFF_RSC + 262144;    // 135004160
    constexpr size_t WS_NEED  = OFF_FLAG + 64;

    float* out = (float*)d_out;                      // FP32 output (and att scratch)
    char* ws = (char*)d_ws;
    float* qkv  = (float*)(ws + OFF_QKV);
    float* xbuf = (float*)(ws + OFF_X);
    float* hbuf = (float*)(ws + OFF_HB);
    float* rc   = (float*)(ws + OFF_RC);
    float* rsn  = (float*)(ws + OFF_RS);
    float* rsc  = (float*)(ws + OFF_RSC);
    int*   flag = (int*)(ws + OFF_FLAG);   // flag[0]=input dtype (1=fp32), flag[1]=1

    int err_stage = 0;
    (void)hipGetLastError();
    #define LCHK(stage) do { if (hipGetLastError() != hipSuccess && err_stage == 0) err_stage = (stage); } while (0)

    if (n_in != 13) err_stage = 90;
    else if (in_sizes[0] != 8388608 || in_sizes[3] != 3145728 || in_sizes[4] != 3072 ||
             in_sizes[5] != 64 || in_sizes[7] != 1024 || in_sizes[9] != 2097152 ||
             in_sizes[10] != 2048 || in_sizes[11] != 2097152 || in_sizes[12] != 1024)
        err_stage = 91;
    else if (ws_size < WS_NEED) err_stage = 92;
    if (err_stage != 0) {
        host_marker_k<<<1, 1, 0, stream>>>(err_stage, out);
        return;
    }

    detect_k<<<1, 256, 0, stream>>>((const unsigned short*)Q, 65536, flag);        LCHK(1);
    rope_tables_k<<<S_, 32, 0, stream>>>(rc, rsn, rsc);                            LCHK(2);
    // qkv = Q @ Wqkv + bqkv  (fp32, tiled)
    {
        dim3 g(3 * D_ / 128, M_ / 128);
        tile_gemm_k<0, false><<<g, 256, 0, stream>>>(
            Q, flag, Wqkv, flag, bqkv, flag, nullptr, qkv, M_, 3 * D_, D_);        LCHK(3);
    }
    // in-place l2norm + scale + rope on q,k
    qkv_post_k<<<(M_ * H_) / 256, 256, 0, stream>>>(
        qkv, qsc, ksc, flag, rc, rsn, rsc);                                        LCHK(4);
    // flash attention -> att staged in d_out (fp32)
    attn_flash_k<<<B_ * H_ * (S_ / 256), 256, 0, stream>>>(qkv, out);              LCHK(5);
    // LayerNorm(att) -> xbuf (qkv region now dead)
    layernorm_k<<<M_, 256, 0, stream>>>(out, ln_g, ln_b, flag, xbuf);              LCHK(6);
    // h = silu(x @ W1 + b1)   (fp32 ws inputs use flag[1]=1)
    {
        dim3 g(FF_ / 128, M_ / 128);
        tile_gemm_k<1, false><<<g, 256, 0, stream>>>(
            xbuf, flag + 1, W1, flag, b1, flag, nullptr, hbuf, M_, FF_, D_);       LCHK(7);
    }
    // out = x + h @ W2 + b2  (overwrites att scratch)
    {
        dim3 g(D_ / 128, M_ / 128);
        tile_gemm_k<0, true><<<g, 256, 0, stream>>>(
            hbuf, flag + 1, W2, flag, b2, flag, xbuf, out, M_, D_, FF_);           LCHK(8);
    }
    host_marker_k<<<1, 1, 0, stream>>>(err_stage, out);
    #undef LCHK
}

// Round 3
// 2193.526 us; speedup vs baseline: 12.3235x; 1.9427x over previous
//
#include <hip/hip_runtime.h>
#include <hip/hip_bf16.h>
#include <math.h>

// TransformerBlock B=4 S=2048 H=16 dh=64 D=1024 FF=2048.
// ROUND 10: GEMMs -> split-bf16 3-product MFMA (fp32 = hi+lo bf16;
// C = Ah.Bh + Ah.Bl + Al.Bh, fp32 MFMA accum; ~2^-16 rel error, fp32-class).
// Weights pre-transposed+split once to WT_hi/lo [N][K] bf16 (dead Vr region).
// 128x128x32 tile, 4 waves x 4x4 frags of mfma_f32_16x16x32_bf16 (m97-verified
// layout: a/b lane l <- tile[l&15][(l>>4)*8+j], C[(l>>4)*4+r][l&15]).
// LDS rows padded to 40 bf16 (<=2-way bank aliasing = free). Attention / LN /
// qkv_post unchanged from round 9. fp32 everywhere outside MFMA operands.

typedef __bf16 bf16_t;
typedef __bf16 bf16x8 __attribute__((ext_vector_type(8)));
typedef __bf16 bf16x4 __attribute__((ext_vector_type(4)));
typedef float  f32x4  __attribute__((ext_vector_type(4)));

#define B_  4
#define S_  2048
#define H_  16
#define DH_ 64
#define D_  1024
#define FF_ 2048
#define M_  (B_ * S_)   // 8192

__device__ __forceinline__ float ldx(const void* p, int i, int f) {
    return f ? ((const float*)p)[i] : (float)((const bf16_t*)p)[i];
}
__device__ __forceinline__ float b2f(unsigned short u) {
    return (float)__builtin_bit_cast(bf16_t, u);
}

// ---- detect input dtype from Q's bit patterns; flag[0]=1 iff fp32; flag[1]=1 ----
__global__ void detect_k(const unsigned short* q, int n, int* flag) {
    const int tid = threadIdx.x;           // single block of 256
    float cnt = 0.f;
    for (int i = tid; i < n; i += 256) {
        const int e = (q[i] >> 7) & 0xFF;  // bf16 exponent field
        if (e >= 134) cnt += 1.f;          // impossible for N(0,1) bf16
    }
    __shared__ float red[256];
    red[tid] = cnt;
    __syncthreads();
    for (int s = 128; s > 0; s >>= 1) {
        if (tid < s) red[tid] += red[tid + s];
        __syncthreads();
    }
    if (tid == 0) { flag[0] = (red[0] > 0.5f) ? 1 : 0; flag[1] = 1; }
}

// ---------------- rope tables ----------------
__global__ void rope_tables_k(float* __restrict__ ct, float* __restrict__ st,
                              float* __restrict__ sct) {
    const int s = blockIdx.x, i = threadIdx.x;   // grid S_, block 32
    const float inv_freq = powf(10000.f, -(float)i / 32.f);
    const float f = (float)s * inv_freq;
    ct[s * 32 + i] = cosf(f);
    st[s * 32 + i] = sinf(f);
    const float base = (2.f * (float)i + 25.6f) / 89.6f;
    const float pw = ((float)s - 1024.f) / 512.f;
    sct[s * 32 + i] = powf(base, pw);
}

// ------------- weight prep: W[K][N] -> WT_hi/lo [N][K] bf16 (LDS-tiled transpose) ----
__global__ __launch_bounds__(256)
void prep_wt_k(const void* __restrict__ W, const int* __restrict__ flag,
               bf16_t* __restrict__ Th, bf16_t* __restrict__ Tl, int K, int N) {
    __shared__ float T[32][33];
    const int tid = threadIdx.x;
    const int n0 = blockIdx.x * 32, k0 = blockIdx.y * 32;
    const int f = flag[0];
#pragma unroll
    for (int i = 0; i < 4; ++i) {
        const int p = i * 256 + tid;
        const int r = p >> 5, c = p & 31;          // r: k-idx, c: n-idx
        T[c][r] = ldx(W, (k0 + r) * N + n0 + c, f);
    }
    __syncthreads();
#pragma unroll
    for (int i = 0; i < 4; ++i) {
        const int p = i * 256 + tid;
        const int r = p >> 5, c = p & 31;          // r: n-idx, c: k-idx
        const float v = T[r][c];
        const bf16_t h = (bf16_t)v;
        Th[(size_t)(n0 + r) * K + k0 + c] = h;
        Tl[(size_t)(n0 + r) * K + k0 + c] = (bf16_t)(v - (float)h);
    }
}

// ------------- split-bf16 MFMA GEMM: C[M,N] = A @ Bw + bias (+silu) (+resid) ------
// A: fp32 (or bf16 input) [M][K]; B: pre-split WT_hi/lo [N][K] bf16.
// 128x128 tile / 256 threads / 4 waves (2x2), BK=32, per wave 4x4 frags 16x16.
template <int ACT, bool RES>
__global__ __launch_bounds__(256)
void gemm3_k(const void* __restrict__ A, const int* __restrict__ fA,
             const bf16_t* __restrict__ BTh, const bf16_t* __restrict__ BTl,
             const void* __restrict__ bias, const int* __restrict__ fbias,
             const float* __restrict__ resid, float* __restrict__ C,
             int M, int N, int K) {
    constexpr int RS = 40;   // padded LDS row stride in bf16 elems (80 B)
    __shared__ __align__(16) bf16_t Ah[128 * RS];
    __shared__ __align__(16) bf16_t Al[128 * RS];
    __shared__ __align__(16) bf16_t Bh[128 * RS];
    __shared__ __align__(16) bf16_t Bl[128 * RS];
    const int tid = threadIdx.x;
    const int lane = tid & 63, wv = tid >> 6;
    const int wm = wv >> 1, wn = wv & 1;
    const int l4 = lane >> 4, l15 = lane & 15;
    const int bm = blockIdx.y * 128, bn = blockIdx.x * 128;
    const int fa = fA[0];
    (void)M;

    f32x4 acc[4][4];
#pragma unroll
    for (int i = 0; i < 4; ++i)
#pragma unroll
        for (int j = 0; j < 4; ++j) acc[i][j] = (f32x4){0.f, 0.f, 0.f, 0.f};

    const int koff = l4 * 8;
    for (int k0 = 0; k0 < K; k0 += 32) {
        __syncthreads();
        // ---- stage A: 128 rows x 32 k fp32 -> hi/lo bf16 ----
#pragma unroll
        for (int i = 0; i < 4; ++i) {
            const int p = i * 256 + tid;
            const int r = p >> 3, c4 = p & 7;
            float4 v;
            if (fa) {
                v = *(const float4*)((const float*)A + (size_t)(bm + r) * K + k0 + c4 * 4);
            } else {
                const ushort4 u = *(const ushort4*)((const unsigned short*)A +
                                                    (size_t)(bm + r) * K + k0 + c4 * 4);
                v = make_float4(b2f(u.x), b2f(u.y), b2f(u.z), b2f(u.w));
            }
            const bf16_t hx = (bf16_t)v.x, hy = (bf16_t)v.y,
                         hz = (bf16_t)v.z, hw = (bf16_t)v.w;
            const bf16x4 hv = {hx, hy, hz, hw};
            const bf16x4 lv = {(bf16_t)(v.x - (float)hx), (bf16_t)(v.y - (float)hy),
                               (bf16_t)(v.z - (float)hz), (bf16_t)(v.w - (float)hw)};
            const int o = r * RS + c4 * 4;
            *(bf16x4*)&Ah[o] = hv;
            *(bf16x4*)&Al[o] = lv;
        }
        // ---- stage B: straight bf16 copy of pre-split WT rows ----
#pragma unroll
        for (int i = 0; i < 4; ++i) {
            const int p = i * 256 + tid;
            const int r = p >> 3, c4 = p & 7;
            const size_t g = (size_t)(bn + r) * K + k0 + c4 * 4;
            const int o = r * RS + c4 * 4;
            *(bf16x4*)&Bh[o] = *(const bf16x4*)(BTh + g);
            *(bf16x4*)&Bl[o] = *(const bf16x4*)(BTl + g);
        }
        __syncthreads();
        // ---- fragments + 3-product MFMA ----
        bf16x8 ahf[4], alf[4], bhf[4], blf[4];
#pragma unroll
        for (int j = 0; j < 4; ++j) {
            const int o = (wn * 64 + j * 16 + l15) * RS + koff;
            bhf[j] = *(const bf16x8*)&Bh[o];
            blf[j] = *(const bf16x8*)&Bl[o];
        }
#pragma unroll
        for (int i = 0; i < 4; ++i) {
            const int o = (wm * 64 + i * 16 + l15) * RS + koff;
            ahf[i] = *(const bf16x8*)&Ah[o];
            alf[i] = *(const bf16x8*)&Al[o];
        }
#pragma unroll
        for (int i = 0; i < 4; ++i)
#pragma unroll
            for (int j = 0; j < 4; ++j) {
                acc[i][j] = __builtin_amdgcn_mfma_f32_16x16x32_bf16(ahf[i], bhf[j], acc[i][j], 0, 0, 0);
                acc[i][j] = __builtin_amdgcn_mfma_f32_16x16x32_bf16(ahf[i], blf[j], acc[i][j], 0, 0, 0);
                acc[i][j] = __builtin_amdgcn_mfma_f32_16x16x32_bf16(alf[i], bhf[j], acc[i][j], 0, 0, 0);
            }
    }

    // ---- epilogue: bias (+silu) (+resid), fp32 stores ----
    const int fc = fbias[0];
#pragma unroll
    for (int j = 0; j < 4; ++j) {
        const int col = bn + wn * 64 + j * 16 + l15;
        const float bv = ldx(bias, col, fc);
#pragma unroll
        for (int i = 0; i < 4; ++i) {
            const int row0 = bm + wm * 64 + i * 16 + l4 * 4;
#pragma unroll
            for (int r = 0; r < 4; ++r) {
                float t = acc[i][j][r] + bv;
                if constexpr (ACT == 1) t = t / (1.f + expf(-t));
                if constexpr (RES) t += resid[(size_t)(row0 + r) * N + col];
                C[(size_t)(row0 + r) * N + col] = t;
            }
        }
    }
}

// ------------- qkv post: in-place l2norm+scale+rope on q,k -------------
__global__ __launch_bounds__(256)
void qkv_post_k(float* __restrict__ qkv,
                const void* __restrict__ qsc, const void* __restrict__ ksc,
                const int* __restrict__ flag,
                const float* __restrict__ ct, const float* __restrict__ st,
                const float* __restrict__ sct) {
    const int id = blockIdx.x * 256 + threadIdx.x;   // [0, M_*H_)
    if (id >= M_ * H_) return;
    const int f = flag[0];
    const int bs = id >> 4, h = id & 15;
    const int s = bs & (S_ - 1);
    float* row = qkv + (size_t)bs * (3 * D_) + h * 192;

    float q[DH_];
    // ---- q ----
    float n2 = 0.f;
#pragma unroll
    for (int d = 0; d < DH_; ++d) { q[d] = row[d]; n2 += q[d] * q[d]; }
    float inv = 1.f / fmaxf(sqrtf(n2), 1e-12f);
#pragma unroll
    for (int d = 0; d < DH_; ++d) q[d] *= inv * ldx(qsc, d, f);
#pragma unroll
    for (int d = 0; d < 32; ++d) {
        const float c = ct[s * 32 + d], sn = st[s * 32 + d], sc = sct[s * 32 + d];
        const float a = q[d], bb = q[d + 32];
        q[d]      = (a * c - bb * sn) * sc;
        q[d + 32] = (bb * c + a * sn) * sc;
    }
#pragma unroll
    for (int d = 0; d < DH_; ++d) row[d] = q[d];
    // ---- k ----
    n2 = 0.f;
#pragma unroll
    for (int d = 0; d < DH_; ++d) { q[d] = row[64 + d]; n2 += q[d] * q[d]; }
    inv = 1.f / fmaxf(sqrtf(n2), 1e-12f);
#pragma unroll
    for (int d = 0; d < DH_; ++d) q[d] *= inv * ldx(ksc, d, f);
#pragma unroll
    for (int d = 0; d < 32; ++d) {
        const float c = ct[s * 32 + d], sn = st[s * 32 + d], isc = 1.f / sct[s * 32 + d];
        const float a = q[d], bb = q[d + 32];
        q[d]      = (a * c - bb * sn) * isc;
        q[d + 32] = (bb * c + a * sn) * isc;
    }
#pragma unroll
    for (int d = 0; d < DH_; ++d) row[64 + d] = q[d];
}

// ------------- flash-style fp32 attention (round-9, unchanged) -------------
__global__ __launch_bounds__(256)
void attn_flash_k(const float* __restrict__ qkv, float* __restrict__ att) {
    __shared__ float4 Ks[64][16];
    __shared__ float4 Vs[64][16];
    const int tid = threadIdx.x;
    const int qt = blockIdx.x & 7;
    const int h  = (blockIdx.x >> 3) & 15;
    const int b  = blockIdx.x >> 7;
    const int sq = qt * 256 + tid;

    const float* qrow = qkv + (size_t)(b * S_ + sq) * (3 * D_) + h * 192;
    float4 q4[16];
#pragma unroll
    for (int i = 0; i < 16; ++i) {
        q4[i] = ((const float4*)qrow)[i];
        q4[i].x *= 0.125f; q4[i].y *= 0.125f; q4[i].z *= 0.125f; q4[i].w *= 0.125f;
    }
    float4 o4[16];
#pragma unroll
    for (int i = 0; i < 16; ++i) o4[i] = make_float4(0.f, 0.f, 0.f, 0.f);
    float sum = 0.f;

    const int lr = tid >> 4, lc = tid & 15;
    for (int j0 = 0; j0 < S_; j0 += 64) {
        __syncthreads();   // previous tile's readers done
#pragma unroll
        for (int i = 0; i < 4; ++i) {
            const int r = lr + i * 16;
            const float* krow = qkv + (size_t)(b * S_ + j0 + r) * (3 * D_) + h * 192 + 64;
            Ks[r][lc] = ((const float4*)krow)[lc];
            Vs[r][lc] = ((const float4*)(krow + 64))[lc];
        }
        __syncthreads();
        for (int j = 0; j < 64; j += 2) {
            float4 a0 = make_float4(0.f, 0.f, 0.f, 0.f);
            float4 a1 = make_float4(0.f, 0.f, 0.f, 0.f);
#pragma unroll
            for (int dd = 0; dd < 16; ++dd) {
                const float4 qq = q4[dd];
                const float4 k0 = Ks[j][dd];
                const float4 k1 = Ks[j + 1][dd];
                a0.x = fmaf(qq.x, k0.x, a0.x); a0.y = fmaf(qq.y, k0.y, a0.y);
                a0.z = fmaf(qq.z, k0.z, a0.z); a0.w = fmaf(qq.w, k0.w, a0.w);
                a1.x = fmaf(qq.x, k1.x, a1.x); a1.y = fmaf(qq.y, k1.y, a1.y);
                a1.z = fmaf(qq.z, k1.z, a1.z); a1.w = fmaf(qq.w, k1.w, a1.w);
            }
            const float p0 = __expf((a0.x + a0.y) + (a0.z + a0.w));
            const float p1 = __expf((a1.x + a1.y) + (a1.z + a1.w));
            sum += p0 + p1;
#pragma unroll
            for (int dd = 0; dd < 16; ++dd) {
                const float4 v0 = Vs[j][dd];
                const float4 v1 = Vs[j + 1][dd];
                o4[dd].x = fmaf(p1, v1.x, fmaf(p0, v0.x, o4[dd].x));
                o4[dd].y = fmaf(p1, v1.y, fmaf(p0, v0.y, o4[dd].y));
                o4[dd].z = fmaf(p1, v1.z, fmaf(p0, v0.z, o4[dd].z));
                o4[dd].w = fmaf(p1, v1.w, fmaf(p0, v0.w, o4[dd].w));
            }
        }
    }
    const float isum = 1.f / sum;
    float4* orow = (float4*)(att + (size_t)(b * S_ + sq) * D_ + h * DH_);
#pragma unroll
    for (int i = 0; i < 16; ++i) {
        float4 o = o4[i];
        o.x *= isum; o.y *= isum; o.z *= isum; o.w *= isum;
        orow[i] = o;
    }
}

// ------------- LayerNorm over D=1024, fp32 in/out -------------
__global__ __launch_bounds__(256)
void layernorm_k(const float* __restrict__ in, const void* __restrict__ g,
                 const void* __restrict__ be, const int* __restrict__ flag,
                 float* __restrict__ xo) {
    const int row = blockIdx.x, tid = threadIdx.x;
    const int lane = tid & 63, wave = tid >> 6;
    const int f = flag[0];
    const float* r = in + (size_t)row * D_;
    float v[4], s = 0.f, ss = 0.f;
#pragma unroll
    for (int i = 0; i < 4; ++i) {
        v[i] = r[tid + i * 256];
        s += v[i]; ss += v[i] * v[i];
    }
#pragma unroll
    for (int msk = 1; msk < 64; msk <<= 1) { s += __shfl_xor(s, msk); ss += __shfl_xor(ss, msk); }
    __shared__ float rs[4], rss[4];
    if (lane == 0) { rs[wave] = s; rss[wave] = ss; }
    __syncthreads();
    s = rs[0] + rs[1] + rs[2] + rs[3];
    ss = rss[0] + rss[1] + rss[2] + rss[3];
    const float mu = s * (1.f / (float)D_);
    const float var = fmaxf(ss * (1.f / (float)D_) - mu * mu, 0.f);
    const float inv = rsqrtf(var + 1e-5f);
    float* xr = xo + (size_t)row * D_;
#pragma unroll
    for (int i = 0; i < 4; ++i) {
        const int c = tid + i * 256;
        xr[c] = (v[i] - mu) * inv * ldx(g, c, f) + ldx(be, c, f);
    }
}

__global__ void host_marker_k(int code, float* __restrict__ out) {
    if (code != 0) out[0] = 1e10f * (float)(1 + code);
}

extern "C" void kernel_launch(void* const* d_in, const int* in_sizes, int n_in,
                              void* d_out, int out_size, void* d_ws, size_t ws_size,
                              hipStream_t stream) {
    (void)out_size;
    const void* Q    = d_in[0];
    const void* Wqkv = d_in[3];
    const void* bqkv = d_in[4];
    const void* qsc  = d_in[5];
    const void* ksc  = d_in[6];
    const void* ln_g = d_in[7];
    const void* ln_b = d_in[8];
    const void* W1   = d_in[9];
    const void* b1   = d_in[10];
    const void* W2   = d_in[11];
    const void* b2   = d_in[12];

    // ws layout (bytes):
    //   [0,100663296)          qkv fp32 -> later xbuf [0,33554432) + hbuf [33554432,100663296)
    //   [100663296,130023424)  WT splits: WqkvT hi/lo, W1T hi/lo, W2T hi/lo (bf16)
    //   [134217728,...)        rope tables + flag
    constexpr size_t OFF_QKV  = 0;
    constexpr size_t OFF_X    = 0;
    constexpr size_t OFF_HB   = 33554432;
    constexpr size_t OFF_WQH  = 100663296;
    constexpr size_t OFF_WQL  = OFF_WQH + 6291456;   // 106954752
    constexpr size_t OFF_W1H  = OFF_WQL + 6291456;   // 113246208
    constexpr size_t OFF_W1L  = OFF_W1H + 4194304;   // 117440512
    constexpr size_t OFF_W2H  = OFF_W1L + 4194304;   // 121634816
    constexpr size_t OFF_W2L  = OFF_W2H + 4194304;   // 125829120 (end 130023424)
    constexpr size_t OFF_RC   = 134217728;
    constexpr size_t OFF_RS   = OFF_RC + 262144;
    constexpr size_t OFF_RSC  = OFF_RS + 262144;
    constexpr size_t OFF_FLAG = OFF_RSC + 262144;    // 135004160
    constexpr size_t WS_NEED  = OFF_FLAG + 64;

    float* out = (float*)d_out;                      // FP32 output (and att scratch)
    char* ws = (char*)d_ws;
    float*  qkv   = (float*)(ws + OFF_QKV);
    float*  xbuf  = (float*)(ws + OFF_X);
    float*  hbuf  = (float*)(ws + OFF_HB);
    bf16_t* wqkvh = (bf16_t*)(ws + OFF_WQH);
    bf16_t* wqkvl = (bf16_t*)(ws + OFF_WQL);
    bf16_t* w1h   = (bf16_t*)(ws + OFF_W1H);
    bf16_t* w1l   = (bf16_t*)(ws + OFF_W1L);
    bf16_t* w2h   = (bf16_t*)(ws + OFF_W2H);
    bf16_t* w2l   = (bf16_t*)(ws + OFF_W2L);
    float*  rc    = (float*)(ws + OFF_RC);
    float*  rsn   = (float*)(ws + OFF_RS);
    float*  rsc   = (float*)(ws + OFF_RSC);
    int*    flag  = (int*)(ws + OFF_FLAG);   // flag[0]=input dtype (1=fp32), flag[1]=1

    int err_stage = 0;
    (void)hipGetLastError();
    #define LCHK(stage) do { if (hipGetLastError() != hipSuccess && err_stage == 0) err_stage = (stage); } while (0)

    if (n_in != 13) err_stage = 90;
    else if (in_sizes[0] != 8388608 || in_sizes[3] != 3145728 || in_sizes[4] != 3072 ||
             in_sizes[5] != 64 || in_sizes[7] != 1024 || in_sizes[9] != 2097152 ||
             in_sizes[10] != 2048 || in_sizes[11] != 2097152 || in_sizes[12] != 1024)
        err_stage = 91;
    else if (ws_size < WS_NEED) err_stage = 92;
    if (err_stage != 0) {
        host_marker_k<<<1, 1, 0, stream>>>(err_stage, out);
        return;
    }

    detect_k<<<1, 256, 0, stream>>>((const unsigned short*)Q, 65536, flag);        LCHK(1);
    rope_tables_k<<<S_, 32, 0, stream>>>(rc, rsn, rsc);                            LCHK(2);
    // weight transpose + hi/lo split (once per launch)
    prep_wt_k<<<dim3(3 * D_ / 32, D_ / 32), 256, 0, stream>>>(
        Wqkv, flag, wqkvh, wqkvl, D_, 3 * D_);                                     LCHK(3);
    prep_wt_k<<<dim3(FF_ / 32, D_ / 32), 256, 0, stream>>>(
        W1, flag, w1h, w1l, D_, FF_);                                              LCHK(4);
    prep_wt_k<<<dim3(D_ / 32, FF_ / 32), 256, 0, stream>>>(
        W2, flag, w2h, w2l, FF_, D_);                                              LCHK(5);
    // qkv = Q @ Wqkv + bqkv  (split-bf16 MFMA)
    gemm3_k<0, false><<<dim3(3 * D_ / 128, M_ / 128), 256, 0, stream>>>(
        Q, flag, wqkvh, wqkvl, bqkv, flag, nullptr, qkv, M_, 3 * D_, D_);          LCHK(6);
    // in-place l2norm + scale + rope on q,k
    qkv_post_k<<<(M_ * H_) / 256, 256, 0, stream>>>(
        qkv, qsc, ksc, flag, rc, rsn, rsc);                                        LCHK(7);
    // flash attention -> att staged in d_out (fp32)
    attn_flash_k<<<B_ * H_ * (S_ / 256), 256, 0, stream>>>(qkv, out);              LCHK(8);
    // LayerNorm(att) -> xbuf (qkv region now dead)
    layernorm_k<<<M_, 256, 0, stream>>>(out, ln_g, ln_b, flag, xbuf);              LCHK(9);
    // h = silu(x @ W1 + b1)
    gemm3_k<1, false><<<dim3(FF_ / 128, M_ / 128), 256, 0, stream>>>(
        xbuf, flag + 1, w1h, w1l, b1, flag, nullptr, hbuf, M_, FF_, D_);           LCHK(10);
    // out = x + h @ W2 + b2  (overwrites att scratch)
    gemm3_k<0, true><<<dim3(D_ / 128, M_ / 128), 256, 0, stream>>>(
        hbuf, flag + 1, w2h, w2l, b2, flag, xbuf, out, M_, D_, FF_);               LCHK(11);
    host_marker_k<<<1, 1, 0, stream>>>(err_stage, out);
    #undef LCHK
}

// Round 4
// 1064.211 us; speedup vs baseline: 25.4009x; 2.0612x over previous
//
#include <hip/hip_runtime.h>
#include <hip/hip_bf16.h>
#include <math.h>

// TransformerBlock B=4 S=2048 H=16 dh=64 D=1024 FF=2048.
// ROUND 11: MFMA attention. logits = 0.125*(q_rot . k_rot) with unit q,k (rope
// scales cancel) => |logit|<=0.125, no-max softmax + plain bf16 Q/K/P/V safe
// (error ~3e-3 post-LN vs 0.0156 floor). K pre-split bf16 [b][h][s][d] in
// qkv_post; V pre-transposed bf16 [b][h][d][s] via vtrans_k. attn: 4 waves x
// 16 q-rows, KB=64 LDS tiles, P via wave-private LDS roundtrip, online sum
// (no rescale), XCD-aware block decode. GEMMs = round-10 split-bf16 3-product
// MFMA. W1/W2 weight prep moved AFTER attention (regions overlay Kb).

typedef __bf16 bf16_t;
typedef __bf16 bf16x8 __attribute__((ext_vector_type(8)));
typedef __bf16 bf16x4 __attribute__((ext_vector_type(4)));
typedef float  f32x4  __attribute__((ext_vector_type(4)));

#define B_  4
#define S_  2048
#define H_  16
#define DH_ 64
#define D_  1024
#define FF_ 2048
#define M_  (B_ * S_)   // 8192

__device__ __forceinline__ float ldx(const void* p, int i, int f) {
    return f ? ((const float*)p)[i] : (float)((const bf16_t*)p)[i];
}
__device__ __forceinline__ float b2f(unsigned short u) {
    return (float)__builtin_bit_cast(bf16_t, u);
}

// ---- detect input dtype from Q's bit patterns; flag[0]=1 iff fp32; flag[1]=1 ----
__global__ void detect_k(const unsigned short* q, int n, int* flag) {
    const int tid = threadIdx.x;           // single block of 256
    float cnt = 0.f;
    for (int i = tid; i < n; i += 256) {
        const int e = (q[i] >> 7) & 0xFF;  // bf16 exponent field
        if (e >= 134) cnt += 1.f;          // impossible for N(0,1) bf16
    }
    __shared__ float red[256];
    red[tid] = cnt;
    __syncthreads();
    for (int s = 128; s > 0; s >>= 1) {
        if (tid < s) red[tid] += red[tid + s];
        __syncthreads();
    }
    if (tid == 0) { flag[0] = (red[0] > 0.5f) ? 1 : 0; flag[1] = 1; }
}

// ---------------- rope tables ----------------
__global__ void rope_tables_k(float* __restrict__ ct, float* __restrict__ st,
                              float* __restrict__ sct) {
    const int s = blockIdx.x, i = threadIdx.x;   // grid S_, block 32
    const float inv_freq = powf(10000.f, -(float)i / 32.f);
    const float f = (float)s * inv_freq;
    ct[s * 32 + i] = cosf(f);
    st[s * 32 + i] = sinf(f);
    const float base = (2.f * (float)i + 25.6f) / 89.6f;
    const float pw = ((float)s - 1024.f) / 512.f;
    sct[s * 32 + i] = powf(base, pw);
}

// ------------- weight prep: W[K][N] -> WT_hi/lo [N][K] bf16 (LDS-tiled transpose) ----
__global__ __launch_bounds__(256)
void prep_wt_k(const void* __restrict__ W, const int* __restrict__ flag,
               bf16_t* __restrict__ Th, bf16_t* __restrict__ Tl, int K, int N) {
    __shared__ float T[32][33];
    const int tid = threadIdx.x;
    const int n0 = blockIdx.x * 32, k0 = blockIdx.y * 32;
    const int f = flag[0];
#pragma unroll
    for (int i = 0; i < 4; ++i) {
        const int p = i * 256 + tid;
        const int r = p >> 5, c = p & 31;          // r: k-idx, c: n-idx
        T[c][r] = ldx(W, (k0 + r) * N + n0 + c, f);
    }
    __syncthreads();
#pragma unroll
    for (int i = 0; i < 4; ++i) {
        const int p = i * 256 + tid;
        const int r = p >> 5, c = p & 31;          // r: n-idx, c: k-idx
        const float v = T[r][c];
        const bf16_t h = (bf16_t)v;
        Th[(size_t)(n0 + r) * K + k0 + c] = h;
        Tl[(size_t)(n0 + r) * K + k0 + c] = (bf16_t)(v - (float)h);
    }
}

// ------------- split-bf16 MFMA GEMM: C[M,N] = A @ Bw + bias (+silu) (+resid) ------
template <int ACT, bool RES>
__global__ __launch_bounds__(256)
void gemm3_k(const void* __restrict__ A, const int* __restrict__ fA,
             const bf16_t* __restrict__ BTh, const bf16_t* __restrict__ BTl,
             const void* __restrict__ bias, const int* __restrict__ fbias,
             const float* __restrict__ resid, float* __restrict__ C,
             int M, int N, int K) {
    constexpr int RS = 40;   // padded LDS row stride in bf16 elems (80 B)
    __shared__ __align__(16) bf16_t Ah[128 * RS];
    __shared__ __align__(16) bf16_t Al[128 * RS];
    __shared__ __align__(16) bf16_t Bh[128 * RS];
    __shared__ __align__(16) bf16_t Bl[128 * RS];
    const int tid = threadIdx.x;
    const int lane = tid & 63, wv = tid >> 6;
    const int wm = wv >> 1, wn = wv & 1;
    const int l4 = lane >> 4, l15 = lane & 15;
    const int bm = blockIdx.y * 128, bn = blockIdx.x * 128;
    const int fa = fA[0];
    (void)M;

    f32x4 acc[4][4];
#pragma unroll
    for (int i = 0; i < 4; ++i)
#pragma unroll
        for (int j = 0; j < 4; ++j) acc[i][j] = (f32x4){0.f, 0.f, 0.f, 0.f};

    const int koff = l4 * 8;
    for (int k0 = 0; k0 < K; k0 += 32) {
        __syncthreads();
        // ---- stage A: 128 rows x 32 k fp32 -> hi/lo bf16 ----
#pragma unroll
        for (int i = 0; i < 4; ++i) {
            const int p = i * 256 + tid;
            const int r = p >> 3, c4 = p & 7;
            float4 v;
            if (fa) {
                v = *(const float4*)((const float*)A + (size_t)(bm + r) * K + k0 + c4 * 4);
            } else {
                const ushort4 u = *(const ushort4*)((const unsigned short*)A +
                                                    (size_t)(bm + r) * K + k0 + c4 * 4);
                v = make_float4(b2f(u.x), b2f(u.y), b2f(u.z), b2f(u.w));
            }
            const bf16_t hx = (bf16_t)v.x, hy = (bf16_t)v.y,
                         hz = (bf16_t)v.z, hw = (bf16_t)v.w;
            const bf16x4 hv = {hx, hy, hz, hw};
            const bf16x4 lv = {(bf16_t)(v.x - (float)hx), (bf16_t)(v.y - (float)hy),
                               (bf16_t)(v.z - (float)hz), (bf16_t)(v.w - (float)hw)};
            const int o = r * RS + c4 * 4;
            *(bf16x4*)&Ah[o] = hv;
            *(bf16x4*)&Al[o] = lv;
        }
        // ---- stage B: straight bf16 copy of pre-split WT rows ----
#pragma unroll
        for (int i = 0; i < 4; ++i) {
            const int p = i * 256 + tid;
            const int r = p >> 3, c4 = p & 7;
            const size_t g = (size_t)(bn + r) * K + k0 + c4 * 4;
            const int o = r * RS + c4 * 4;
            *(bf16x4*)&Bh[o] = *(const bf16x4*)(BTh + g);
            *(bf16x4*)&Bl[o] = *(const bf16x4*)(BTl + g);
        }
        __syncthreads();
        // ---- fragments + 3-product MFMA ----
        bf16x8 ahf[4], alf[4], bhf[4], blf[4];
#pragma unroll
        for (int j = 0; j < 4; ++j) {
            const int o = (wn * 64 + j * 16 + l15) * RS + koff;
            bhf[j] = *(const bf16x8*)&Bh[o];
            blf[j] = *(const bf16x8*)&Bl[o];
        }
#pragma unroll
        for (int i = 0; i < 4; ++i) {
            const int o = (wm * 64 + i * 16 + l15) * RS + koff;
            ahf[i] = *(const bf16x8*)&Ah[o];
            alf[i] = *(const bf16x8*)&Al[o];
        }
#pragma unroll
        for (int i = 0; i < 4; ++i)
#pragma unroll
            for (int j = 0; j < 4; ++j) {
                acc[i][j] = __builtin_amdgcn_mfma_f32_16x16x32_bf16(ahf[i], bhf[j], acc[i][j], 0, 0, 0);
                acc[i][j] = __builtin_amdgcn_mfma_f32_16x16x32_bf16(ahf[i], blf[j], acc[i][j], 0, 0, 0);
                acc[i][j] = __builtin_amdgcn_mfma_f32_16x16x32_bf16(alf[i], bhf[j], acc[i][j], 0, 0, 0);
            }
    }

    // ---- epilogue: bias (+silu) (+resid), fp32 stores ----
    const int fc = fbias[0];
#pragma unroll
    for (int j = 0; j < 4; ++j) {
        const int col = bn + wn * 64 + j * 16 + l15;
        const float bv = ldx(bias, col, fc);
#pragma unroll
        for (int i = 0; i < 4; ++i) {
            const int row0 = bm + wm * 64 + i * 16 + l4 * 4;
#pragma unroll
            for (int r = 0; r < 4; ++r) {
                float t = acc[i][j][r] + bv;
                if constexpr (ACT == 1) t = t / (1.f + expf(-t));
                if constexpr (RES) t += resid[(size_t)(row0 + r) * N + col];
                C[(size_t)(row0 + r) * N + col] = t;
            }
        }
    }
}

// ------------- qkv post: l2norm+scale+rope; q fp32 in-place, k -> Kb bf16 -------------
__global__ __launch_bounds__(256)
void qkv_post_k(float* __restrict__ qkv,
                const void* __restrict__ qsc, const void* __restrict__ ksc,
                const int* __restrict__ flag,
                const float* __restrict__ ct, const float* __restrict__ st,
                const float* __restrict__ sct, bf16_t* __restrict__ Kb) {
    const int id = blockIdx.x * 256 + threadIdx.x;   // [0, M_*H_)
    if (id >= M_ * H_) return;
    const int f = flag[0];
    const int bs = id >> 4, h = id & 15;
    const int s = bs & (S_ - 1), b = bs >> 11;
    float* row = qkv + (size_t)bs * (3 * D_) + h * 192;

    float q[DH_];
    // ---- q: fp32 writeback (read by attn frag build) ----
    float n2 = 0.f;
#pragma unroll
    for (int d = 0; d < DH_; ++d) { q[d] = row[d]; n2 += q[d] * q[d]; }
    float inv = 1.f / fmaxf(sqrtf(n2), 1e-12f);
#pragma unroll
    for (int d = 0; d < DH_; ++d) q[d] *= inv * ldx(qsc, d, f);
#pragma unroll
    for (int d = 0; d < 32; ++d) {
        const float c = ct[s * 32 + d], sn = st[s * 32 + d], sc = sct[s * 32 + d];
        const float a = q[d], bb = q[d + 32];
        q[d]      = (a * c - bb * sn) * sc;
        q[d + 32] = (bb * c + a * sn) * sc;
    }
#pragma unroll
    for (int d = 0; d < DH_; ++d) row[d] = q[d];
    // ---- k: bf16 out to Kb[b][h][s][d] (no fp32 writeback) ----
    n2 = 0.f;
#pragma unroll
    for (int d = 0; d < DH_; ++d) { q[d] = row[64 + d]; n2 += q[d] * q[d]; }
    inv = 1.f / fmaxf(sqrtf(n2), 1e-12f);
#pragma unroll
    for (int d = 0; d < DH_; ++d) q[d] *= inv * ldx(ksc, d, f);
#pragma unroll
    for (int d = 0; d < 32; ++d) {
        const float c = ct[s * 32 + d], sn = st[s * 32 + d], isc = 1.f / sct[s * 32 + d];
        const float a = q[d], bb = q[d + 32];
        q[d]      = (a * c - bb * sn) * isc;
        q[d + 32] = (bb * c + a * sn) * isc;
    }
    bf16_t* kr = Kb + ((size_t)(b * H_ + h) * S_ + s) * DH_;
#pragma unroll
    for (int d8 = 0; d8 < 8; ++d8) {
        bf16x8 v;
#pragma unroll
        for (int j = 0; j < 8; ++j) v[j] = (bf16_t)q[d8 * 8 + j];
        *(bf16x8*)(kr + d8 * 8) = v;
    }
}

// ------------- V transpose: qkv v-region fp32 [s][..] -> Vt bf16 [b][h][d][s] ---------
__global__ __launch_bounds__(256)
void vtrans_k(const float* __restrict__ qkv, bf16_t* __restrict__ Vt) {
    __shared__ float T[32][65];
    const int tid = threadIdx.x;
    const int s0 = blockIdx.x * 32;          // S_/32 blocks
    const int h  = blockIdx.y;
    const int b  = blockIdx.z;
    {
        const int r = tid >> 3, d0 = (tid & 7) * 8;
        const float* vrow = qkv + (size_t)(b * S_ + s0 + r) * (3 * D_) + h * 192 + 128;
        const float4 a = *(const float4*)(vrow + d0);
        const float4 c = *(const float4*)(vrow + d0 + 4);
        T[r][d0 + 0] = a.x; T[r][d0 + 1] = a.y; T[r][d0 + 2] = a.z; T[r][d0 + 3] = a.w;
        T[r][d0 + 4] = c.x; T[r][d0 + 5] = c.y; T[r][d0 + 6] = c.z; T[r][d0 + 7] = c.w;
    }
    __syncthreads();
    {
        const int d = tid >> 2, sl0 = (tid & 3) * 8;
        bf16x8 o;
#pragma unroll
        for (int j = 0; j < 8; ++j) o[j] = (bf16_t)T[sl0 + j][d];
        *(bf16x8*)(Vt + ((size_t)(b * H_ + h) * DH_ + d) * S_ + s0 + sl0) = o;
    }
}

// ------------- MFMA flash attention -------------
// Block = 256 thr = 4 waves, each wave 16 q-rows of one (b,h); K/V tiles of 64
// in LDS (RS=72 pad). No-max softmax (|logit|<=0.125). P roundtrip via
// wave-private LDS. XCD-aware decode: 2048 blocks = 8 xcd * 8 bh * 32 qt.
__global__ __launch_bounds__(256)
void attn_mfma_k(const float* __restrict__ qkv, const bf16_t* __restrict__ Kb,
                 const bf16_t* __restrict__ Vt, float* __restrict__ att) {
    constexpr int RS = 72;
    __shared__ __align__(16) bf16_t Ks[64 * RS];
    __shared__ __align__(16) bf16_t Vs[64 * RS];       // Vs[d][kj]
    __shared__ __align__(16) bf16_t Ps[4][16 * RS];    // per-wave P tile
    const int tid = threadIdx.x;
    const int lane = tid & 63, w = tid >> 6;
    const int l15 = lane & 15, l4 = lane >> 4;
    const int bid = blockIdx.x;
    const int bh = (bid & 7) * 8 + (bid >> 8);   // same (b,h) stays on one XCD
    const int qt = (bid >> 3) & 31;
    const int b = bh >> 4, h = bh & 15;
    const int q0 = qt * 64 + w * 16;

    // Q fragments (bf16, softmax scale folded), built once
    bf16x8 qf[2];
    {
        const float* qrow = qkv + (size_t)(b * S_ + q0 + l15) * (3 * D_) + h * 192;
#pragma unroll
        for (int t = 0; t < 2; ++t) {
            const float4 v0 = *(const float4*)(qrow + t * 32 + l4 * 8);
            const float4 v1 = *(const float4*)(qrow + t * 32 + l4 * 8 + 4);
            bf16x8 q8;
            q8[0] = (bf16_t)(v0.x * 0.125f); q8[1] = (bf16_t)(v0.y * 0.125f);
            q8[2] = (bf16_t)(v0.z * 0.125f); q8[3] = (bf16_t)(v0.w * 0.125f);
            q8[4] = (bf16_t)(v1.x * 0.125f); q8[5] = (bf16_t)(v1.y * 0.125f);
            q8[6] = (bf16_t)(v1.z * 0.125f); q8[7] = (bf16_t)(v1.w * 0.125f);
            qf[t] = q8;
        }
    }
    f32x4 of[4];
#pragma unroll
    for (int i = 0; i < 4; ++i) of[i] = (f32x4){0.f, 0.f, 0.f, 0.f};
    float psum[4] = {0.f, 0.f, 0.f, 0.f};

    const bf16_t* Kg = Kb + (size_t)bh * S_ * DH_;
    const bf16_t* Vg = Vt + (size_t)bh * DH_ * S_;
    const int sr = tid >> 2, sc = (tid & 3) * 16;

    for (int j0 = 0; j0 < S_; j0 += 64) {
        __syncthreads();
        *(bf16x8*)&Ks[sr * RS + sc]     = *(const bf16x8*)(Kg + (size_t)(j0 + sr) * DH_ + sc);
        *(bf16x8*)&Ks[sr * RS + sc + 8] = *(const bf16x8*)(Kg + (size_t)(j0 + sr) * DH_ + sc + 8);
        *(bf16x8*)&Vs[sr * RS + sc]     = *(const bf16x8*)(Vg + (size_t)sr * S_ + j0 + sc);
        *(bf16x8*)&Vs[sr * RS + sc + 8] = *(const bf16x8*)(Vg + (size_t)sr * S_ + j0 + sc + 8);
        __syncthreads();

        // QK^T: C[16q x 64kj] in 4 frags
        f32x4 sf[4];
#pragma unroll
        for (int i = 0; i < 4; ++i) sf[i] = (f32x4){0.f, 0.f, 0.f, 0.f};
#pragma unroll
        for (int t = 0; t < 2; ++t)
#pragma unroll
            for (int fj = 0; fj < 4; ++fj) {
                const bf16x8 kf = *(const bf16x8*)&Ks[(fj * 16 + l15) * RS + t * 32 + l4 * 8];
                sf[fj] = __builtin_amdgcn_mfma_f32_16x16x32_bf16(qf[t], kf, sf[fj], 0, 0, 0);
            }
        // exp (no max-sub) + P -> LDS (C-layout position)
#pragma unroll
        for (int fj = 0; fj < 4; ++fj)
#pragma unroll
            for (int r = 0; r < 4; ++r) {
                const float p = __expf(sf[fj][r]);
                const bf16_t pb = (bf16_t)p;
                psum[r] += (float)pb;
                Ps[w][(l4 * 4 + r) * RS + fj * 16 + l15] = pb;
            }
        // PV: O[16q x 64d] += P[16x64] @ V[64x64]
#pragma unroll
        for (int t = 0; t < 2; ++t) {
            const bf16x8 pf = *(const bf16x8*)&Ps[w][l15 * RS + t * 32 + l4 * 8];
#pragma unroll
            for (int fd = 0; fd < 4; ++fd) {
                const bf16x8 vf = *(const bf16x8*)&Vs[(fd * 16 + l15) * RS + t * 32 + l4 * 8];
                of[fd] = __builtin_amdgcn_mfma_f32_16x16x32_bf16(pf, vf, of[fd], 0, 0, 0);
            }
        }
    }
    // row-sum reduce across the 16 lanes sharing a row group
#pragma unroll
    for (int r = 0; r < 4; ++r)
#pragma unroll
        for (int msk = 1; msk < 16; msk <<= 1) psum[r] += __shfl_xor(psum[r], msk);
    // store O / sum
#pragma unroll
    for (int r = 0; r < 4; ++r) {
        const float inv = 1.f / psum[r];
        float* orow = att + (size_t)(b * S_ + q0 + l4 * 4 + r) * D_ + h * DH_;
#pragma unroll
        for (int fd = 0; fd < 4; ++fd) orow[fd * 16 + l15] = of[fd][r] * inv;
    }
}

// ------------- LayerNorm over D=1024, fp32 in/out -------------
__global__ __launch_bounds__(256)
void layernorm_k(const float* __restrict__ in, const void* __restrict__ g,
                 const void* __restrict__ be, const int* __restrict__ flag,
                 float* __restrict__ xo) {
    const int row = blockIdx.x, tid = threadIdx.x;
    const int lane = tid & 63, wave = tid >> 6;
    const int f = flag[0];
    const float* r = in + (size_t)row * D_;
    float v[4], s = 0.f, ss = 0.f;
#pragma unroll
    for (int i = 0; i < 4; ++i) {
        v[i] = r[tid + i * 256];
        s += v[i]; ss += v[i] * v[i];
    }
#pragma unroll
    for (int msk = 1; msk < 64; msk <<= 1) { s += __shfl_xor(s, msk); ss += __shfl_xor(ss, msk); }
    __shared__ float rs[4], rss[4];
    if (lane == 0) { rs[wave] = s; rss[wave] = ss; }
    __syncthreads();
    s = rs[0] + rs[1] + rs[2] + rs[3];
    ss = rss[0] + rss[1] + rss[2] + rss[3];
    const float mu = s * (1.f / (float)D_);
    const float var = fmaxf(ss * (1.f / (float)D_) - mu * mu, 0.f);
    const float inv = rsqrtf(var + 1e-5f);
    float* xr = xo + (size_t)row * D_;
#pragma unroll
    for (int i = 0; i < 4; ++i) {
        const int c = tid + i * 256;
        xr[c] = (v[i] - mu) * inv * ldx(g, c, f) + ldx(be, c, f);
    }
}

__global__ void host_marker_k(int code, float* __restrict__ out) {
    if (code != 0) out[0] = 1e10f * (float)(1 + code);
}

extern "C" void kernel_launch(void* const* d_in, const int* in_sizes, int n_in,
                              void* d_out, int out_size, void* d_ws, size_t ws_size,
                              hipStream_t stream) {
    (void)out_size;
    const void* Q    = d_in[0];
    const void* Wqkv = d_in[3];
    const void* bqkv = d_in[4];
    const void* qsc  = d_in[5];
    const void* ksc  = d_in[6];
    const void* ln_g = d_in[7];
    const void* ln_b = d_in[8];
    const void* W1   = d_in[9];
    const void* b1   = d_in[10];
    const void* W2   = d_in[11];
    const void* b2   = d_in[12];

    // ws layout (bytes), time-multiplexed:
    //   [0,100663296)          qkv fp32; after attn: xbuf [0,32M) + hbuf [32M,96M)
    //   [100663296,113246208)  WqkvT hi/lo (dead after qkv gemm)
    //        after attn:       W1T hi/lo + W2T hi/lo [100663296,117440512)
    //   [113246208,130023424)  Kb bf16 [B][H][S][64] (qkv_post -> attn)
    //   [130023424,146800640)  Vt bf16 [B][H][64][S] (vtrans -> attn)
    //   [146800640,...]        rope tables + flag
    constexpr size_t OFF_QKV  = 0;
    constexpr size_t OFF_X    = 0;
    constexpr size_t OFF_HB   = 33554432;
    constexpr size_t OFF_WQH  = 100663296;
    constexpr size_t OFF_WQL  = 106954752;
    constexpr size_t OFF_KB   = 113246208;
    constexpr size_t OFF_VT   = 130023424;
    constexpr size_t OFF_W1H  = 100663296;
    constexpr size_t OFF_W1L  = 104857600;
    constexpr size_t OFF_W2H  = 109051904;
    constexpr size_t OFF_W2L  = 113246208;
    constexpr size_t OFF_RC   = 146800640;
    constexpr size_t OFF_RS   = OFF_RC + 262144;
    constexpr size_t OFF_RSC  = OFF_RS + 262144;
    constexpr size_t OFF_FLAG = OFF_RSC + 262144;    // 147587072
    constexpr size_t WS_NEED  = OFF_FLAG + 64;       // ~140.8 MB (proven 151.8 MB)

    float* out = (float*)d_out;                      // FP32 output (and att scratch)
    char* ws = (char*)d_ws;
    float*  qkv   = (float*)(ws + OFF_QKV);
    float*  xbuf  = (float*)(ws + OFF_X);
    float*  hbuf  = (float*)(ws + OFF_HB);
    bf16_t* wqkvh = (bf16_t*)(ws + OFF_WQH);
    bf16_t* wqkvl = (bf16_t*)(ws + OFF_WQL);
    bf16_t* kb    = (bf16_t*)(ws + OFF_KB);
    bf16_t* vtb   = (bf16_t*)(ws + OFF_VT);
    bf16_t* w1h   = (bf16_t*)(ws + OFF_W1H);
    bf16_t* w1l   = (bf16_t*)(ws + OFF_W1L);
    bf16_t* w2h   = (bf16_t*)(ws + OFF_W2H);
    bf16_t* w2l   = (bf16_t*)(ws + OFF_W2L);
    float*  rc    = (float*)(ws + OFF_RC);
    float*  rsn   = (float*)(ws + OFF_RS);
    float*  rsc   = (float*)(ws + OFF_RSC);
    int*    flag  = (int*)(ws + OFF_FLAG);   // flag[0]=input dtype (1=fp32), flag[1]=1

    int err_stage = 0;
    (void)hipGetLastError();
    #define LCHK(stage) do { if (hipGetLastError() != hipSuccess && err_stage == 0) err_stage = (stage); } while (0)

    if (n_in != 13) err_stage = 90;
    else if (in_sizes[0] != 8388608 || in_sizes[3] != 3145728 || in_sizes[4] != 3072 ||
             in_sizes[5] != 64 || in_sizes[7] != 1024 || in_sizes[9] != 2097152 ||
             in_sizes[10] != 2048 || in_sizes[11] != 2097152 || in_sizes[12] != 1024)
        err_stage = 91;
    else if (ws_size < WS_NEED) err_stage = 92;
    if (err_stage != 0) {
        host_marker_k<<<1, 1, 0, stream>>>(err_stage, out);
        return;
    }

    detect_k<<<1, 256, 0, stream>>>((const unsigned short*)Q, 65536, flag);        LCHK(1);
    rope_tables_k<<<S_, 32, 0, stream>>>(rc, rsn, rsc);                            LCHK(2);
    // Wqkv transpose + split
    prep_wt_k<<<dim3(3 * D_ / 32, D_ / 32), 256, 0, stream>>>(
        Wqkv, flag, wqkvh, wqkvl, D_, 3 * D_);                                     LCHK(3);
    // qkv = Q @ Wqkv + bqkv  (split-bf16 MFMA)
    gemm3_k<0, false><<<dim3(3 * D_ / 128, M_ / 128), 256, 0, stream>>>(
        Q, flag, wqkvh, wqkvl, bqkv, flag, nullptr, qkv, M_, 3 * D_, D_);          LCHK(4);
    // l2norm + scale + rope; q fp32 in-place, k -> Kb bf16
    qkv_post_k<<<(M_ * H_) / 256, 256, 0, stream>>>(
        qkv, qsc, ksc, flag, rc, rsn, rsc, kb);                                    LCHK(5);
    // v -> Vt bf16 transposed
    vtrans_k<<<dim3(S_ / 32, H_, B_), 256, 0, stream>>>(qkv, vtb);                 LCHK(6);
    // MFMA flash attention -> att staged in d_out (fp32)
    attn_mfma_k<<<B_ * H_ * (S_ / 64), 256, 0, stream>>>(qkv, kb, vtb, out);       LCHK(7);
    // LayerNorm(att) -> xbuf (qkv region now dead)
    layernorm_k<<<M_, 256, 0, stream>>>(out, ln_g, ln_b, flag, xbuf);              LCHK(8);
    // W1/W2 transpose + split (regions overlay dead Wqkv/Kb)
    prep_wt_k<<<dim3(FF_ / 32, D_ / 32), 256, 0, stream>>>(
        W1, flag, w1h, w1l, D_, FF_);                                              LCHK(9);
    prep_wt_k<<<dim3(D_ / 32, FF_ / 32), 256, 0, stream>>>(
        W2, flag, w2h, w2l, FF_, D_);                                              LCHK(10);
    // h = silu(x @ W1 + b1)
    gemm3_k<1, false><<<dim3(FF_ / 128, M_ / 128), 256, 0, stream>>>(
        xbuf, flag + 1, w1h, w1l, b1, flag, nullptr, hbuf, M_, FF_, D_);           LCHK(11);
    // out = x + h @ W2 + b2  (overwrites att scratch)
    gemm3_k<0, true><<<dim3(D_ / 128, M_ / 128), 256, 0, stream>>>(
        hbuf, flag + 1, w2h, w2l, b2, flag, xbuf, out, M_, D_, FF_);               LCHK(12);
    host_marker_k<<<1, 1, 0, stream>>>(err_stage, out);
    #undef LCHK
}

// Round 5
// 658.849 us; speedup vs baseline: 41.0290x; 1.6153x over previous
//
#include <hip/hip_runtime.h>
#include <hip/hip_bf16.h>
#include <math.h>

// TransformerBlock B=4 S=2048 H=16 dh=64 D=1024 FF=2048.
// ROUND 12: GEMMs -> single-product fp16 MFMA in the m97-verified structure:
// 128x128 tile, BK=32, global_load_lds width=16 staging, linear LDS dest with
// pre-swizzled per-lane global source (chunk ^= (row>>1)&3) so frag ds_read_b128
// is 2-way bank-aliased (free). A/B pre-converted to fp16 once: Q->q16 (cvt16),
// W->WT fp16 [N][K] (prep_wt16), LN emits x16, FF1 epilogue emits h16.
// fp16 rounding (2^-11) adds ~2e-3 post-LN error -- under the 0.031 absmax.
// Attention / qkv_post / vtrans unchanged from round 11.

typedef __bf16 bf16_t;
typedef __bf16 bf16x8 __attribute__((ext_vector_type(8)));
typedef _Float16 f16_t;
typedef _Float16 f16x8 __attribute__((ext_vector_type(8)));
typedef float  f32x4  __attribute__((ext_vector_type(4)));

#define B_  4
#define S_  2048
#define H_  16
#define DH_ 64
#define D_  1024
#define FF_ 2048
#define M_  (B_ * S_)   // 8192

__device__ __forceinline__ float ldx(const void* p, int i, int f) {
    return f ? ((const float*)p)[i] : (float)((const bf16_t*)p)[i];
}
__device__ __forceinline__ float b2f(unsigned short u) {
    return (float)__builtin_bit_cast(bf16_t, u);
}
// async global->LDS, 16B per lane; lds must be wave-uniform base (lane*16 applied by HW)
__device__ __forceinline__ void gll16(const void* g, const void* lds) {
    __builtin_amdgcn_global_load_lds(
        (const __attribute__((address_space(1))) unsigned int*)g,
        (__attribute__((address_space(3))) unsigned int*)lds, 16, 0, 0);
}

// ---- detect input dtype from Q's bit patterns; flag[0]=1 iff fp32; flag[1]=1 ----
__global__ void detect_k(const unsigned short* q, int n, int* flag) {
    const int tid = threadIdx.x;           // single block of 256
    float cnt = 0.f;
    for (int i = tid; i < n; i += 256) {
        const int e = (q[i] >> 7) & 0xFF;  // bf16 exponent field
        if (e >= 134) cnt += 1.f;          // impossible for N(0,1) bf16
    }
    __shared__ float red[256];
    red[tid] = cnt;
    __syncthreads();
    for (int s = 128; s > 0; s >>= 1) {
        if (tid < s) red[tid] += red[tid + s];
        __syncthreads();
    }
    if (tid == 0) { flag[0] = (red[0] > 0.5f) ? 1 : 0; flag[1] = 1; }
}

// ---------------- rope tables ----------------
__global__ void rope_tables_k(float* __restrict__ ct, float* __restrict__ st,
                              float* __restrict__ sct) {
    const int s = blockIdx.x, i = threadIdx.x;   // grid S_, block 32
    const float inv_freq = powf(10000.f, -(float)i / 32.f);
    const float f = (float)s * inv_freq;
    ct[s * 32 + i] = cosf(f);
    st[s * 32 + i] = sinf(f);
    const float base = (2.f * (float)i + 25.6f) / 89.6f;
    const float pw = ((float)s - 1024.f) / 512.f;
    sct[s * 32 + i] = powf(base, pw);
}

// ------------- cvt: fp32/bf16 -> fp16, 8 elems/thread -------------
__global__ __launch_bounds__(256)
void cvt16_k(const void* __restrict__ in, const int* __restrict__ flag,
             f16_t* __restrict__ o, int n8) {
    const int id = blockIdx.x * 256 + threadIdx.x;
    if (id >= n8) return;
    f16x8 v;
    if (flag[0]) {
        const float4 a = ((const float4*)in)[id * 2];
        const float4 b = ((const float4*)in)[id * 2 + 1];
        v[0] = (f16_t)a.x; v[1] = (f16_t)a.y; v[2] = (f16_t)a.z; v[3] = (f16_t)a.w;
        v[4] = (f16_t)b.x; v[5] = (f16_t)b.y; v[6] = (f16_t)b.z; v[7] = (f16_t)b.w;
    } else {
        const ushort4 a = ((const ushort4*)in)[id * 2];
        const ushort4 b = ((const ushort4*)in)[id * 2 + 1];
        v[0] = (f16_t)b2f(a.x); v[1] = (f16_t)b2f(a.y); v[2] = (f16_t)b2f(a.z); v[3] = (f16_t)b2f(a.w);
        v[4] = (f16_t)b2f(b.x); v[5] = (f16_t)b2f(b.y); v[6] = (f16_t)b2f(b.z); v[7] = (f16_t)b2f(b.w);
    }
    ((f16x8*)o)[id] = v;
}

// ------------- weight prep: W[K][N] -> WT fp16 [N][K] (LDS-tiled transpose) ----
__global__ __launch_bounds__(256)
void prep_wt16_k(const void* __restrict__ W, const int* __restrict__ flag,
                 f16_t* __restrict__ T16, int K, int N) {
    __shared__ float T[32][33];
    const int tid = threadIdx.x;
    const int n0 = blockIdx.x * 32, k0 = blockIdx.y * 32;
    const int f = flag[0];
#pragma unroll
    for (int i = 0; i < 4; ++i) {
        const int p = i * 256 + tid;
        const int r = p >> 5, c = p & 31;          // r: k-idx, c: n-idx
        T[c][r] = ldx(W, (k0 + r) * N + n0 + c, f);
    }
    __syncthreads();
#pragma unroll
    for (int i = 0; i < 4; ++i) {
        const int p = i * 256 + tid;
        const int r = p >> 5, c = p & 31;          // r: n-idx, c: k-idx
        T16[(size_t)(n0 + r) * K + k0 + c] = (f16_t)T[r][c];
    }
}

// ------------- fp16 MFMA GEMM (m97 structure): C = A @ B^T(+bias)(+silu)(+resid) ----
// A16 [M][K] fp16, B16 [N][K] fp16. 128x128 tile / 4 waves (2x2) / BK=32.
// Staging: global_load_lds 16B/lane, LDS linear [128][32]; per-lane global chunk
// pre-swizzled (ck = c ^ ((row>>1)&3)) so frag reads are 2-way bank-aliased (free).
template <int ACT, int OUT16, bool RES>
__global__ __launch_bounds__(256)
void gemm16_k(const f16_t* __restrict__ A16, const f16_t* __restrict__ B16,
              const void* __restrict__ bias, const int* __restrict__ fbias,
              const float* __restrict__ resid, float* __restrict__ C,
              f16_t* __restrict__ C16, int M, int N, int K) {
    __shared__ __align__(16) f16_t As[128 * 32];
    __shared__ __align__(16) f16_t Bs[128 * 32];
    const int tid = threadIdx.x;
    const int lane = tid & 63, w = tid >> 6;
    const int l15 = lane & 15, l4 = lane >> 4;
    const int wm = w >> 1, wn = w & 1;
    const int bm = blockIdx.y * 128, bn = blockIdx.x * 128;
    const int sr = lane >> 2, sc = lane & 3;
    const int ck = sc ^ ((sr >> 1) & 3);           // swizzled global chunk
    const int rsel = (l15 >> 1) & 3;               // frag-read swizzle select
    (void)M;

    f32x4 acc[4][4];
#pragma unroll
    for (int i = 0; i < 4; ++i)
#pragma unroll
        for (int j = 0; j < 4; ++j) acc[i][j] = (f32x4){0.f, 0.f, 0.f, 0.f};

    for (int k0 = 0; k0 < K; k0 += 32) {
        __syncthreads();                           // readers of previous tile done
#pragma unroll
        for (int i = 0; i < 2; ++i) {
            const int t = w * 2 + i;               // issue 0..7, 16 rows each
            const int r = t * 16 + sr;
            gll16(A16 + (size_t)(bm + r) * K + k0 + ck * 8, As + t * 512);
            gll16(B16 + (size_t)(bn + r) * K + k0 + ck * 8, Bs + t * 512);
        }
        __syncthreads();                           // drains vmcnt -> tiles ready
        f16x8 af[4], bfr[4];
#pragma unroll
        for (int i = 0; i < 4; ++i) {
            const int r = wm * 64 + i * 16 + l15;
            af[i] = *(const f16x8*)&As[r * 32 + ((l4 ^ rsel) << 3)];
        }
#pragma unroll
        for (int j = 0; j < 4; ++j) {
            const int r = wn * 64 + j * 16 + l15;
            bfr[j] = *(const f16x8*)&Bs[r * 32 + ((l4 ^ rsel) << 3)];
        }
#pragma unroll
        for (int i = 0; i < 4; ++i)
#pragma unroll
            for (int j = 0; j < 4; ++j)
                acc[i][j] = __builtin_amdgcn_mfma_f32_16x16x32_f16(af[i], bfr[j], acc[i][j], 0, 0, 0);
    }

    // ---- epilogue: bias (+silu) (+resid); fp32 or fp16 out ----
    const int fc = fbias[0];
#pragma unroll
    for (int j = 0; j < 4; ++j) {
        const int col = bn + wn * 64 + j * 16 + l15;
        const float bv = ldx(bias, col, fc);
#pragma unroll
        for (int i = 0; i < 4; ++i) {
            const int row0 = bm + wm * 64 + i * 16 + l4 * 4;
#pragma unroll
            for (int r = 0; r < 4; ++r) {
                float t = acc[i][j][r] + bv;
                if constexpr (ACT == 1) t = t / (1.f + expf(-t));
                if constexpr (RES) t += resid[(size_t)(row0 + r) * N + col];
                if constexpr (OUT16) C16[(size_t)(row0 + r) * N + col] = (f16_t)t;
                else                 C[(size_t)(row0 + r) * N + col] = t;
            }
        }
    }
}

// ------------- qkv post: l2norm+scale+rope; q fp32 in-place, k -> Kb bf16 -------------
__global__ __launch_bounds__(256)
void qkv_post_k(float* __restrict__ qkv,
                const void* __restrict__ qsc, const void* __restrict__ ksc,
                const int* __restrict__ flag,
                const float* __restrict__ ct, const float* __restrict__ st,
                const float* __restrict__ sct, bf16_t* __restrict__ Kb) {
    const int id = blockIdx.x * 256 + threadIdx.x;   // [0, M_*H_)
    if (id >= M_ * H_) return;
    const int f = flag[0];
    const int bs = id >> 4, h = id & 15;
    const int s = bs & (S_ - 1), b = bs >> 11;
    float* row = qkv + (size_t)bs * (3 * D_) + h * 192;

    float q[DH_];
    // ---- q: fp32 writeback (read by attn frag build) ----
    float n2 = 0.f;
#pragma unroll
    for (int d = 0; d < DH_; ++d) { q[d] = row[d]; n2 += q[d] * q[d]; }
    float inv = 1.f / fmaxf(sqrtf(n2), 1e-12f);
#pragma unroll
    for (int d = 0; d < DH_; ++d) q[d] *= inv * ldx(qsc, d, f);
#pragma unroll
    for (int d = 0; d < 32; ++d) {
        const float c = ct[s * 32 + d], sn = st[s * 32 + d], sc = sct[s * 32 + d];
        const float a = q[d], bb = q[d + 32];
        q[d]      = (a * c - bb * sn) * sc;
        q[d + 32] = (bb * c + a * sn) * sc;
    }
#pragma unroll
    for (int d = 0; d < DH_; ++d) row[d] = q[d];
    // ---- k: bf16 out to Kb[b][h][s][d] (no fp32 writeback) ----
    n2 = 0.f;
#pragma unroll
    for (int d = 0; d < DH_; ++d) { q[d] = row[64 + d]; n2 += q[d] * q[d]; }
    inv = 1.f / fmaxf(sqrtf(n2), 1e-12f);
#pragma unroll
    for (int d = 0; d < DH_; ++d) q[d] *= inv * ldx(ksc, d, f);
#pragma unroll
    for (int d = 0; d < 32; ++d) {
        const float c = ct[s * 32 + d], sn = st[s * 32 + d], isc = 1.f / sct[s * 32 + d];
        const float a = q[d], bb = q[d + 32];
        q[d]      = (a * c - bb * sn) * isc;
        q[d + 32] = (bb * c + a * sn) * isc;
    }
    bf16_t* kr = Kb + ((size_t)(b * H_ + h) * S_ + s) * DH_;
#pragma unroll
    for (int d8 = 0; d8 < 8; ++d8) {
        bf16x8 v;
#pragma unroll
        for (int j = 0; j < 8; ++j) v[j] = (bf16_t)q[d8 * 8 + j];
        *(bf16x8*)(kr + d8 * 8) = v;
    }
}

// ------------- V transpose: qkv v-region fp32 [s][..] -> Vt bf16 [b][h][d][s] ---------
__global__ __launch_bounds__(256)
void vtrans_k(const float* __restrict__ qkv, bf16_t* __restrict__ Vt) {
    __shared__ float T[32][65];
    const int tid = threadIdx.x;
    const int s0 = blockIdx.x * 32;          // S_/32 blocks
    const int h  = blockIdx.y;
    const int b  = blockIdx.z;
    {
        const int r = tid >> 3, d0 = (tid & 7) * 8;
        const float* vrow = qkv + (size_t)(b * S_ + s0 + r) * (3 * D_) + h * 192 + 128;
        const float4 a = *(const float4*)(vrow + d0);
        const float4 c = *(const float4*)(vrow + d0 + 4);
        T[r][d0 + 0] = a.x; T[r][d0 + 1] = a.y; T[r][d0 + 2] = a.z; T[r][d0 + 3] = a.w;
        T[r][d0 + 4] = c.x; T[r][d0 + 5] = c.y; T[r][d0 + 6] = c.z; T[r][d0 + 7] = c.w;
    }
    __syncthreads();
    {
        const int d = tid >> 2, sl0 = (tid & 3) * 8;
        bf16x8 o;
#pragma unroll
        for (int j = 0; j < 8; ++j) o[j] = (bf16_t)T[sl0 + j][d];
        *(bf16x8*)(Vt + ((size_t)(b * H_ + h) * DH_ + d) * S_ + s0 + sl0) = o;
    }
}

// ------------- MFMA flash attention (round-11, unchanged) -------------
__global__ __launch_bounds__(256)
void attn_mfma_k(const float* __restrict__ qkv, const bf16_t* __restrict__ Kb,
                 const bf16_t* __restrict__ Vt, float* __restrict__ att) {
    constexpr int RS = 72;
    __shared__ __align__(16) bf16_t Ks[64 * RS];
    __shared__ __align__(16) bf16_t Vs[64 * RS];       // Vs[d][kj]
    __shared__ __align__(16) bf16_t Ps[4][16 * RS];    // per-wave P tile
    const int tid = threadIdx.x;
    const int lane = tid & 63, w = tid >> 6;
    const int l15 = lane & 15, l4 = lane >> 4;
    const int bid = blockIdx.x;
    const int bh = (bid & 7) * 8 + (bid >> 8);   // same (b,h) stays on one XCD
    const int qt = (bid >> 3) & 31;
    const int b = bh >> 4, h = bh & 15;
    const int q0 = qt * 64 + w * 16;

    // Q fragments (bf16, softmax scale folded), built once
    bf16x8 qf[2];
    {
        const float* qrow = qkv + (size_t)(b * S_ + q0 + l15) * (3 * D_) + h * 192;
#pragma unroll
        for (int t = 0; t < 2; ++t) {
            const float4 v0 = *(const float4*)(qrow + t * 32 + l4 * 8);
            const float4 v1 = *(const float4*)(qrow + t * 32 + l4 * 8 + 4);
            bf16x8 q8;
            q8[0] = (bf16_t)(v0.x * 0.125f); q8[1] = (bf16_t)(v0.y * 0.125f);
            q8[2] = (bf16_t)(v0.z * 0.125f); q8[3] = (bf16_t)(v0.w * 0.125f);
            q8[4] = (bf16_t)(v1.x * 0.125f); q8[5] = (bf16_t)(v1.y * 0.125f);
            q8[6] = (bf16_t)(v1.z * 0.125f); q8[7] = (bf16_t)(v1.w * 0.125f);
            qf[t] = q8;
        }
    }
    f32x4 of[4];
#pragma unroll
    for (int i = 0; i < 4; ++i) of[i] = (f32x4){0.f, 0.f, 0.f, 0.f};
    float psum[4] = {0.f, 0.f, 0.f, 0.f};

    const bf16_t* Kg = Kb + (size_t)bh * S_ * DH_;
    const bf16_t* Vg = Vt + (size_t)bh * DH_ * S_;
    const int sr = tid >> 2, sc = (tid & 3) * 16;

    for (int j0 = 0; j0 < S_; j0 += 64) {
        __syncthreads();
        *(bf16x8*)&Ks[sr * RS + sc]     = *(const bf16x8*)(Kg + (size_t)(j0 + sr) * DH_ + sc);
        *(bf16x8*)&Ks[sr * RS + sc + 8] = *(const bf16x8*)(Kg + (size_t)(j0 + sr) * DH_ + sc + 8);
        *(bf16x8*)&Vs[sr * RS + sc]     = *(const bf16x8*)(Vg + (size_t)sr * S_ + j0 + sc);
        *(bf16x8*)&Vs[sr * RS + sc + 8] = *(const bf16x8*)(Vg + (size_t)sr * S_ + j0 + sc + 8);
        __syncthreads();

        // QK^T: C[16q x 64kj] in 4 frags
        f32x4 sf[4];
#pragma unroll
        for (int i = 0; i < 4; ++i) sf[i] = (f32x4){0.f, 0.f, 0.f, 0.f};
#pragma unroll
        for (int t = 0; t < 2; ++t)
#pragma unroll
            for (int fj = 0; fj < 4; ++fj) {
                const bf16x8 kf = *(const bf16x8*)&Ks[(fj * 16 + l15) * RS + t * 32 + l4 * 8];
                sf[fj] = __builtin_amdgcn_mfma_f32_16x16x32_bf16(qf[t], kf, sf[fj], 0, 0, 0);
            }
        // exp (no max-sub) + P -> LDS (C-layout position)
#pragma unroll
        for (int fj = 0; fj < 4; ++fj)
#pragma unroll
            for (int r = 0; r < 4; ++r) {
                const float p = __expf(sf[fj][r]);
                const bf16_t pb = (bf16_t)p;
                psum[r] += (float)pb;
                Ps[w][(l4 * 4 + r) * RS + fj * 16 + l15] = pb;
            }
        // PV: O[16q x 64d] += P[16x64] @ V[64x64]
#pragma unroll
        for (int t = 0; t < 2; ++t) {
            const bf16x8 pf = *(const bf16x8*)&Ps[w][l15 * RS + t * 32 + l4 * 8];
#pragma unroll
            for (int fd = 0; fd < 4; ++fd) {
                const bf16x8 vf = *(const bf16x8*)&Vs[(fd * 16 + l15) * RS + t * 32 + l4 * 8];
                of[fd] = __builtin_amdgcn_mfma_f32_16x16x32_bf16(pf, vf, of[fd], 0, 0, 0);
            }
        }
    }
    // row-sum reduce across the 16 lanes sharing a row group
#pragma unroll
    for (int r = 0; r < 4; ++r)
#pragma unroll
        for (int msk = 1; msk < 16; msk <<= 1) psum[r] += __shfl_xor(psum[r], msk);
    // store O / sum
#pragma unroll
    for (int r = 0; r < 4; ++r) {
        const float inv = 1.f / psum[r];
        float* orow = att + (size_t)(b * S_ + q0 + l4 * 4 + r) * D_ + h * DH_;
#pragma unroll
        for (int fd = 0; fd < 4; ++fd) orow[fd * 16 + l15] = of[fd][r] * inv;
    }
}

// ------------- LayerNorm over D=1024, fp32 + fp16 out -------------
__global__ __launch_bounds__(256)
void layernorm_k(const float* __restrict__ in, const void* __restrict__ g,
                 const void* __restrict__ be, const int* __restrict__ flag,
                 float* __restrict__ xo, f16_t* __restrict__ x16) {
    const int row = blockIdx.x, tid = threadIdx.x;
    const int lane = tid & 63, wave = tid >> 6;
    const int f = flag[0];
    const float* r = in + (size_t)row * D_;
    float v[4], s = 0.f, ss = 0.f;
#pragma unroll
    for (int i = 0; i < 4; ++i) {
        v[i] = r[tid + i * 256];
        s += v[i]; ss += v[i] * v[i];
    }
#pragma unroll
    for (int msk = 1; msk < 64; msk <<= 1) { s += __shfl_xor(s, msk); ss += __shfl_xor(ss, msk); }
    __shared__ float rs[4], rss[4];
    if (lane == 0) { rs[wave] = s; rss[wave] = ss; }
    __syncthreads();
    s = rs[0] + rs[1] + rs[2] + rs[3];
    ss = rss[0] + rss[1] + rss[2] + rss[3];
    const float mu = s * (1.f / (float)D_);
    const float var = fmaxf(ss * (1.f / (float)D_) - mu * mu, 0.f);
    const float inv = rsqrtf(var + 1e-5f);
    float* xr = xo + (size_t)row * D_;
    f16_t* hr = x16 + (size_t)row * D_;
#pragma unroll
    for (int i = 0; i < 4; ++i) {
        const int c = tid + i * 256;
        const float t = (v[i] - mu) * inv * ldx(g, c, f) + ldx(be, c, f);
        xr[c] = t;
        hr[c] = (f16_t)t;
    }
}

__global__ void host_marker_k(int code, float* __restrict__ out) {
    if (code != 0) out[0] = 1e10f * (float)(1 + code);
}

extern "C" void kernel_launch(void* const* d_in, const int* in_sizes, int n_in,
                              void* d_out, int out_size, void* d_ws, size_t ws_size,
                              hipStream_t stream) {
    (void)out_size;
    const void* Q    = d_in[0];
    const void* Wqkv = d_in[3];
    const void* bqkv = d_in[4];
    const void* qsc  = d_in[5];
    const void* ksc  = d_in[6];
    const void* ln_g = d_in[7];
    const void* ln_b = d_in[8];
    const void* W1   = d_in[9];
    const void* b1   = d_in[10];
    const void* W2   = d_in[11];
    const void* b2   = d_in[12];

    // ws layout (bytes), time-multiplexed:
    //   [0,100663296)   qkv fp32; after attn: xbuf f32 [0,32M) + x16 [32M,48M) + h16 [48M,80M)
    //   [100663296,...) wqkv16 6M | w116 4M | w216 4M   (fp16 [N][K])
    //   [115343360,...) q16 fp16 16M (dead after QKV gemm) = Kb bf16 16M (after)
    //   [132120576,...) Vt bf16 16M
    //   [148897792,...) rope tables + flag
    constexpr size_t OFF_QKV  = 0;
    constexpr size_t OFF_X    = 0;
    constexpr size_t OFF_X16  = 33554432;
    constexpr size_t OFF_H16  = 50331648;
    constexpr size_t OFF_WQ16 = 100663296;
    constexpr size_t OFF_W116 = 106954752;
    constexpr size_t OFF_W216 = 111149056;
    constexpr size_t OFF_Q16  = 115343360;
    constexpr size_t OFF_KB   = 115343360;           // overlays q16 (stream-serial)
    constexpr size_t OFF_VT   = 132120576;
    constexpr size_t OFF_RC   = 148897792;
    constexpr size_t OFF_RS   = OFF_RC + 262144;
    constexpr size_t OFF_RSC  = OFF_RS + 262144;
    constexpr size_t OFF_FLAG = OFF_RSC + 262144;    // 149684224
    constexpr size_t WS_NEED  = OFF_FLAG + 64;       // ~142.8 MB (proven 151.8 MB)

    float* out = (float*)d_out;                      // FP32 output (and att scratch)
    char* ws = (char*)d_ws;
    float*  qkv   = (float*)(ws + OFF_QKV);
    float*  xbuf  = (float*)(ws + OFF_X);
    f16_t*  x16   = (f16_t*)(ws + OFF_X16);
    f16_t*  h16   = (f16_t*)(ws + OFF_H16);
    f16_t*  wq16  = (f16_t*)(ws + OFF_WQ16);
    f16_t*  w116  = (f16_t*)(ws + OFF_W116);
    f16_t*  w216  = (f16_t*)(ws + OFF_W216);
    f16_t*  q16   = (f16_t*)(ws + OFF_Q16);
    bf16_t* kb    = (bf16_t*)(ws + OFF_KB);
    bf16_t* vtb   = (bf16_t*)(ws + OFF_VT);
    float*  rc    = (float*)(ws + OFF_RC);
    float*  rsn   = (float*)(ws + OFF_RS);
    float*  rsc   = (float*)(ws + OFF_RSC);
    int*    flag  = (int*)(ws + OFF_FLAG);   // flag[0]=input dtype (1=fp32), flag[1]=1

    int err_stage = 0;
    (void)hipGetLastError();
    #define LCHK(stage) do { if (hipGetLastError() != hipSuccess && err_stage == 0) err_stage = (stage); } while (0)

    if (n_in != 13) err_stage = 90;
    else if (in_sizes[0] != 8388608 || in_sizes[3] != 3145728 || in_sizes[4] != 3072 ||
             in_sizes[5] != 64 || in_sizes[7] != 1024 || in_sizes[9] != 2097152 ||
             in_sizes[10] != 2048 || in_sizes[11] != 2097152 || in_sizes[12] != 1024)
        err_stage = 91;
    else if (ws_size < WS_NEED) err_stage = 92;
    if (err_stage != 0) {
        host_marker_k<<<1, 1, 0, stream>>>(err_stage, out);
        return;
    }

    detect_k<<<1, 256, 0, stream>>>((const unsigned short*)Q, 65536, flag);        LCHK(1);
    rope_tables_k<<<S_, 32, 0, stream>>>(rc, rsn, rsc);                            LCHK(2);
    // fp16 conversions / transposes
    cvt16_k<<<(M_ * D_ / 8) / 256, 256, 0, stream>>>(Q, flag, q16, M_ * D_ / 8);   LCHK(3);
    prep_wt16_k<<<dim3(3 * D_ / 32, D_ / 32), 256, 0, stream>>>(
        Wqkv, flag, wq16, D_, 3 * D_);                                             LCHK(4);
    prep_wt16_k<<<dim3(FF_ / 32, D_ / 32), 256, 0, stream>>>(
        W1, flag, w116, D_, FF_);                                                  LCHK(5);
    prep_wt16_k<<<dim3(D_ / 32, FF_ / 32), 256, 0, stream>>>(
        W2, flag, w216, FF_, D_);                                                  LCHK(6);
    // qkv = Q @ Wqkv + bqkv  (fp16 MFMA, fp32 out)
    gemm16_k<0, 0, false><<<dim3(3 * D_ / 128, M_ / 128), 256, 0, stream>>>(
        q16, wq16, bqkv, flag, nullptr, qkv, nullptr, M_, 3 * D_, D_);             LCHK(7);
    // l2norm + scale + rope; q fp32 in-place, k -> Kb bf16 (overlays dead q16)
    qkv_post_k<<<(M_ * H_) / 256, 256, 0, stream>>>(
        qkv, qsc, ksc, flag, rc, rsn, rsc, kb);                                    LCHK(8);
    // v -> Vt bf16 transposed
    vtrans_k<<<dim3(S_ / 32, H_, B_), 256, 0, stream>>>(qkv, vtb);                 LCHK(9);
    // MFMA flash attention -> att staged in d_out (fp32)
    attn_mfma_k<<<B_ * H_ * (S_ / 64), 256, 0, stream>>>(qkv, kb, vtb, out);       LCHK(10);
    // LayerNorm(att) -> xbuf fp32 + x16 fp16 (qkv region now dead)
    layernorm_k<<<M_, 256, 0, stream>>>(out, ln_g, ln_b, flag, xbuf, x16);         LCHK(11);
    // h16 = silu(x @ W1 + b1)  (fp16 out)
    gemm16_k<1, 1, false><<<dim3(FF_ / 128, M_ / 128), 256, 0, stream>>>(
        x16, w116, b1, flag, nullptr, nullptr, h16, M_, FF_, D_);                  LCHK(12);
    // out = x + h @ W2 + b2  (fp32 out, overwrites att scratch)
    gemm16_k<0, 0, true><<<dim3(D_ / 128, M_ / 128), 256, 0, stream>>>(
        h16, w216, b2, flag, xbuf, out, nullptr, M_, D_, FF_);                     LCHK(13);
    host_marker_k<<<1, 1, 0, stream>>>(err_stage, out);
    #undef LCHK
}

// Round 6
// 637.803 us; speedup vs baseline: 42.3828x; 1.0330x over previous
//
#include <hip/hip_runtime.h>
#include <hip/hip_bf16.h>
#include <math.h>

// TransformerBlock B=4 S=2048 H=16 dh=64 D=1024 FF=2048.
// ROUND 13: attention v2 -- global_load_lds K/V staging (linear LDS dest,
// inverse-swizzled per-lane global source, XOR-swizzled reads), double-buffered
// 2-phase pipeline (stage next tile before compute, one barrier/tile), P-store
// bank swizzle slot=(kj>>3)^((q>>1)&7), setprio around MFMA, Q pre-scaled bf16
// (Qb) built in qkv_post. Pipeline byte cuts: QKV GEMM emits fp16 qkv16;
// qkv_post/vtrans read fp16; LN emits only x16; FF2 residual from x16.
// GEMMs = round-12 fp16 MFMA m97-structure. att scratch in ws[0,32M).

typedef __bf16 bf16_t;
typedef __bf16 bf16x8 __attribute__((ext_vector_type(8)));
typedef _Float16 f16_t;
typedef _Float16 f16x8 __attribute__((ext_vector_type(8)));
typedef float  f32x4  __attribute__((ext_vector_type(4)));

#define B_  4
#define S_  2048
#define H_  16
#define DH_ 64
#define D_  1024
#define FF_ 2048
#define M_  (B_ * S_)   // 8192

__device__ __forceinline__ float ldx(const void* p, int i, int f) {
    return f ? ((const float*)p)[i] : (float)((const bf16_t*)p)[i];
}
__device__ __forceinline__ float b2f(unsigned short u) {
    return (float)__builtin_bit_cast(bf16_t, u);
}
// async global->LDS, 16B per lane; lds base wave-uniform (lane*16 applied by HW)
__device__ __forceinline__ void gll16(const void* g, const void* lds) {
    __builtin_amdgcn_global_load_lds(
        (const __attribute__((address_space(1))) unsigned int*)g,
        (__attribute__((address_space(3))) unsigned int*)lds, 16, 0, 0);
}

// ---- detect input dtype from Q's bit patterns; flag[0]=1 iff fp32; flag[1]=1 ----
__global__ void detect_k(const unsigned short* q, int n, int* flag) {
    const int tid = threadIdx.x;           // single block of 256
    float cnt = 0.f;
    for (int i = tid; i < n; i += 256) {
        const int e = (q[i] >> 7) & 0xFF;  // bf16 exponent field
        if (e >= 134) cnt += 1.f;          // impossible for N(0,1) bf16
    }
    __shared__ float red[256];
    red[tid] = cnt;
    __syncthreads();
    for (int s = 128; s > 0; s >>= 1) {
        if (tid < s) red[tid] += red[tid + s];
        __syncthreads();
    }
    if (tid == 0) { flag[0] = (red[0] > 0.5f) ? 1 : 0; flag[1] = 1; }
}

// ---------------- rope tables ----------------
__global__ void rope_tables_k(float* __restrict__ ct, float* __restrict__ st,
                              float* __restrict__ sct) {
    const int s = blockIdx.x, i = threadIdx.x;   // grid S_, block 32
    const float inv_freq = powf(10000.f, -(float)i / 32.f);
    const float f = (float)s * inv_freq;
    ct[s * 32 + i] = cosf(f);
    st[s * 32 + i] = sinf(f);
    const float base = (2.f * (float)i + 25.6f) / 89.6f;
    const float pw = ((float)s - 1024.f) / 512.f;
    sct[s * 32 + i] = powf(base, pw);
}

// ------------- cvt: fp32/bf16 -> fp16, 8 elems/thread -------------
__global__ __launch_bounds__(256)
void cvt16_k(const void* __restrict__ in, const int* __restrict__ flag,
             f16_t* __restrict__ o, int n8) {
    const int id = blockIdx.x * 256 + threadIdx.x;
    if (id >= n8) return;
    f16x8 v;
    if (flag[0]) {
        const float4 a = ((const float4*)in)[id * 2];
        const float4 b = ((const float4*)in)[id * 2 + 1];
        v[0] = (f16_t)a.x; v[1] = (f16_t)a.y; v[2] = (f16_t)a.z; v[3] = (f16_t)a.w;
        v[4] = (f16_t)b.x; v[5] = (f16_t)b.y; v[6] = (f16_t)b.z; v[7] = (f16_t)b.w;
    } else {
        const ushort4 a = ((const ushort4*)in)[id * 2];
        const ushort4 b = ((const ushort4*)in)[id * 2 + 1];
        v[0] = (f16_t)b2f(a.x); v[1] = (f16_t)b2f(a.y); v[2] = (f16_t)b2f(a.z); v[3] = (f16_t)b2f(a.w);
        v[4] = (f16_t)b2f(b.x); v[5] = (f16_t)b2f(b.y); v[6] = (f16_t)b2f(b.z); v[7] = (f16_t)b2f(b.w);
    }
    ((f16x8*)o)[id] = v;
}

// ------------- weight prep: W[K][N] -> WT fp16 [N][K] (LDS-tiled transpose) ----
__global__ __launch_bounds__(256)
void prep_wt16_k(const void* __restrict__ W, const int* __restrict__ flag,
                 f16_t* __restrict__ T16, int K, int N) {
    __shared__ float T[32][33];
    const int tid = threadIdx.x;
    const int n0 = blockIdx.x * 32, k0 = blockIdx.y * 32;
    const int f = flag[0];
#pragma unroll
    for (int i = 0; i < 4; ++i) {
        const int p = i * 256 + tid;
        const int r = p >> 5, c = p & 31;          // r: k-idx, c: n-idx
        T[c][r] = ldx(W, (k0 + r) * N + n0 + c, f);
    }
    __syncthreads();
#pragma unroll
    for (int i = 0; i < 4; ++i) {
        const int p = i * 256 + tid;
        const int r = p >> 5, c = p & 31;          // r: n-idx, c: k-idx
        T16[(size_t)(n0 + r) * K + k0 + c] = (f16_t)T[r][c];
    }
}

// ------------- fp16 MFMA GEMM (m97 structure): C = A @ B^T(+bias)(+silu)(+resid) ----
// RES: 0 none, 1 fp32 resid, 2 fp16 resid. OUT16: write C16 fp16 else C fp32.
template <int ACT, int OUT16, int RES>
__global__ __launch_bounds__(256)
void gemm16_k(const f16_t* __restrict__ A16, const f16_t* __restrict__ B16,
              const void* __restrict__ bias, const int* __restrict__ fbias,
              const float* __restrict__ residf, const f16_t* __restrict__ resid16,
              float* __restrict__ C, f16_t* __restrict__ C16, int M, int N, int K) {
    __shared__ __align__(16) f16_t As[128 * 32];
    __shared__ __align__(16) f16_t Bs[128 * 32];
    const int tid = threadIdx.x;
    const int lane = tid & 63, w = tid >> 6;
    const int l15 = lane & 15, l4 = lane >> 4;
    const int wm = w >> 1, wn = w & 1;
    const int bm = blockIdx.y * 128, bn = blockIdx.x * 128;
    const int sr = lane >> 2, sc = lane & 3;
    const int ck = sc ^ ((sr >> 1) & 3);           // swizzled global chunk
    const int rsel = (l15 >> 1) & 3;               // frag-read swizzle select
    (void)M;

    f32x4 acc[4][4];
#pragma unroll
    for (int i = 0; i < 4; ++i)
#pragma unroll
        for (int j = 0; j < 4; ++j) acc[i][j] = (f32x4){0.f, 0.f, 0.f, 0.f};

    for (int k0 = 0; k0 < K; k0 += 32) {
        __syncthreads();                           // readers of previous tile done
#pragma unroll
        for (int i = 0; i < 2; ++i) {
            const int t = w * 2 + i;               // issue 0..7, 16 rows each
            const int r = t * 16 + sr;
            gll16(A16 + (size_t)(bm + r) * K + k0 + ck * 8, As + t * 512);
            gll16(B16 + (size_t)(bn + r) * K + k0 + ck * 8, Bs + t * 512);
        }
        __syncthreads();                           // drains vmcnt -> tiles ready
        f16x8 af[4], bfr[4];
#pragma unroll
        for (int i = 0; i < 4; ++i) {
            const int r = wm * 64 + i * 16 + l15;
            af[i] = *(const f16x8*)&As[r * 32 + ((l4 ^ rsel) << 3)];
        }
#pragma unroll
        for (int j = 0; j < 4; ++j) {
            const int r = wn * 64 + j * 16 + l15;
            bfr[j] = *(const f16x8*)&Bs[r * 32 + ((l4 ^ rsel) << 3)];
        }
#pragma unroll
        for (int i = 0; i < 4; ++i)
#pragma unroll
            for (int j = 0; j < 4; ++j)
                acc[i][j] = __builtin_amdgcn_mfma_f32_16x16x32_f16(af[i], bfr[j], acc[i][j], 0, 0, 0);
    }

    // ---- epilogue: bias (+silu) (+resid); fp32 or fp16 out ----
    const int fc = fbias[0];
#pragma unroll
    for (int j = 0; j < 4; ++j) {
        const int col = bn + wn * 64 + j * 16 + l15;
        const float bv = ldx(bias, col, fc);
#pragma unroll
        for (int i = 0; i < 4; ++i) {
            const int row0 = bm + wm * 64 + i * 16 + l4 * 4;
#pragma unroll
            for (int r = 0; r < 4; ++r) {
                float t = acc[i][j][r] + bv;
                if constexpr (ACT == 1) t = t / (1.f + expf(-t));
                if constexpr (RES == 1) t += residf[(size_t)(row0 + r) * N + col];
                if constexpr (RES == 2) t += (float)resid16[(size_t)(row0 + r) * N + col];
                if constexpr (OUT16) C16[(size_t)(row0 + r) * N + col] = (f16_t)t;
                else                 C[(size_t)(row0 + r) * N + col] = t;
            }
        }
    }
}

// ------------- qkv post: l2norm+scale+rope; q -> Qb bf16 (x0.125), k -> Kb bf16 -------
__global__ __launch_bounds__(256)
void qkv_post_k(const f16_t* __restrict__ qkv16,
                const void* __restrict__ qsc, const void* __restrict__ ksc,
                const int* __restrict__ flag,
                const float* __restrict__ ct, const float* __restrict__ st,
                const float* __restrict__ sct,
                bf16_t* __restrict__ Qb, bf16_t* __restrict__ Kb) {
    const int id = blockIdx.x * 256 + threadIdx.x;   // [0, M_*H_)
    if (id >= M_ * H_) return;
    const int f = flag[0];
    const int bs = id >> 4, h = id & 15;
    const int s = bs & (S_ - 1), b = bs >> 11;
    const f16_t* row = qkv16 + (size_t)bs * (3 * D_) + h * 192;

    float q[DH_];
    // ---- q ----
    float n2 = 0.f;
#pragma unroll
    for (int d8 = 0; d8 < 8; ++d8) {
        const f16x8 v = *(const f16x8*)(row + d8 * 8);
#pragma unroll
        for (int j = 0; j < 8; ++j) { q[d8 * 8 + j] = (float)v[j]; n2 += q[d8*8+j]*q[d8*8+j]; }
    }
    float inv = 1.f / fmaxf(sqrtf(n2), 1e-12f);
#pragma unroll
    for (int d = 0; d < DH_; ++d) q[d] *= inv * ldx(qsc, d, f);
#pragma unroll
    for (int d = 0; d < 32; ++d) {
        const float c = ct[s * 32 + d], sn = st[s * 32 + d], sc = sct[s * 32 + d];
        const float a = q[d], bb = q[d + 32];
        q[d]      = (a * c - bb * sn) * sc;
        q[d + 32] = (bb * c + a * sn) * sc;
    }
    bf16_t* qr = Qb + ((size_t)(b * H_ + h) * S_ + s) * DH_;
#pragma unroll
    for (int d8 = 0; d8 < 8; ++d8) {
        bf16x8 v;
#pragma unroll
        for (int j = 0; j < 8; ++j) v[j] = (bf16_t)(q[d8 * 8 + j] * 0.125f);
        *(bf16x8*)(qr + d8 * 8) = v;
    }
    // ---- k ----
    n2 = 0.f;
#pragma unroll
    for (int d8 = 0; d8 < 8; ++d8) {
        const f16x8 v = *(const f16x8*)(row + 64 + d8 * 8);
#pragma unroll
        for (int j = 0; j < 8; ++j) { q[d8 * 8 + j] = (float)v[j]; n2 += q[d8*8+j]*q[d8*8+j]; }
    }
    inv = 1.f / fmaxf(sqrtf(n2), 1e-12f);
#pragma unroll
    for (int d = 0; d < DH_; ++d) q[d] *= inv * ldx(ksc, d, f);
#pragma unroll
    for (int d = 0; d < 32; ++d) {
        const float c = ct[s * 32 + d], sn = st[s * 32 + d], isc = 1.f / sct[s * 32 + d];
        const float a = q[d], bb = q[d + 32];
        q[d]      = (a * c - bb * sn) * isc;
        q[d + 32] = (bb * c + a * sn) * isc;
    }
    bf16_t* kr = Kb + ((size_t)(b * H_ + h) * S_ + s) * DH_;
#pragma unroll
    for (int d8 = 0; d8 < 8; ++d8) {
        bf16x8 v;
#pragma unroll
        for (int j = 0; j < 8; ++j) v[j] = (bf16_t)q[d8 * 8 + j];
        *(bf16x8*)(kr + d8 * 8) = v;
    }
}

// ------------- V transpose: qkv16 v-region fp16 -> Vt bf16 [b][h][d][s] ---------
__global__ __launch_bounds__(256)
void vtrans_k(const f16_t* __restrict__ qkv16, bf16_t* __restrict__ Vt) {
    __shared__ float T[32][65];
    const int tid = threadIdx.x;
    const int s0 = blockIdx.x * 32;          // S_/32 blocks
    const int h  = blockIdx.y;
    const int b  = blockIdx.z;
    {
        const int r = tid >> 3, d0 = (tid & 7) * 8;
        const f16_t* vrow = qkv16 + (size_t)(b * S_ + s0 + r) * (3 * D_) + h * 192 + 128;
        const f16x8 v = *(const f16x8*)(vrow + d0);
#pragma unroll
        for (int j = 0; j < 8; ++j) T[r][d0 + j] = (float)v[j];
    }
    __syncthreads();
    {
        const int d = tid >> 2, sl0 = (tid & 3) * 8;
        bf16x8 o;
#pragma unroll
        for (int j = 0; j < 8; ++j) o[j] = (bf16_t)T[sl0 + j][d];
        *(bf16x8*)(Vt + ((size_t)(b * H_ + h) * DH_ + d) * S_ + s0 + sl0) = o;
    }
}

// ------------- MFMA flash attention v2 -------------
// 4 waves x 16 q-rows; K/V double-buffered [64][64] bf16 linear LDS via
// global_load_lds (source chunk pre-swizzled c^=(row&7); reads XOR the same);
// P in swizzled [16][64] per-wave LDS (slot=(kj>>3)^((q>>1)&7)). One barrier
// per tile; next tile staged before compute. No-max softmax (|logit|<=0.125).
__global__ __launch_bounds__(256)
void attn_mfma_k(const bf16_t* __restrict__ Qb, const bf16_t* __restrict__ Kb,
                 const bf16_t* __restrict__ Vt, float* __restrict__ att) {
    __shared__ __align__(16) bf16_t Ks[2][64 * 64];
    __shared__ __align__(16) bf16_t Vs[2][64 * 64];
    __shared__ __align__(16) bf16_t Ps[4][16 * 64];
    const int tid = threadIdx.x;
    const int lane = tid & 63, w = tid >> 6;
    const int l15 = lane & 15, l4 = lane >> 4;
    const int bid = blockIdx.x;
    const int bh = (bid & 7) * 8 + (bid >> 8);   // same (b,h) stays on one XCD
    const int qt = (bid >> 3) & 31;
    const int b = bh >> 4, h = bh & 15;
    const int q0 = qt * 64 + w * 16;

    const bf16_t* Qg = Qb + (size_t)bh * S_ * DH_;
    const bf16_t* Kg = Kb + (size_t)bh * S_ * DH_;
    const bf16_t* Vg = Vt + (size_t)bh * DH_ * S_;

    // Q fragments (already bf16, 0.125-folded)
    bf16x8 qf[2];
#pragma unroll
    for (int t = 0; t < 2; ++t)
        qf[t] = *(const bf16x8*)(Qg + (size_t)(q0 + l15) * DH_ + t * 32 + l4 * 8);

    f32x4 of[4];
#pragma unroll
    for (int i = 0; i < 4; ++i) of[i] = (f32x4){0.f, 0.f, 0.f, 0.f};
    float psum[4] = {0.f, 0.f, 0.f, 0.f};

    const int srow = lane >> 3;                    // 0..7 within 8-row group
    const int sck  = (lane & 7) ^ (srow & 7);      // inverse-swizzled source chunk

#define STAGE(bufi, j0) do {                                                        \
    _Pragma("unroll")                                                               \
    for (int i_ = 0; i_ < 2; ++i_) {                                                \
        const int rbase = w * 16 + i_ * 8;                                          \
        const int rr = rbase + srow;                                                \
        gll16(Kg + (size_t)((j0) + rr) * DH_ + sck * 8, &Ks[bufi][rbase * 64]);     \
        gll16(Vg + (size_t)rr * S_ + (j0) + sck * 8, &Vs[bufi][rbase * 64]);        \
    } } while (0)

    STAGE(0, 0);
    __syncthreads();
    int cur = 0;
    for (int jt = 0; jt < S_ / 64; ++jt) {
        if (jt < S_ / 64 - 1) STAGE(cur ^ 1, (jt + 1) * 64);
        // ---- QK^T: C[16q x 64kj] ----
        f32x4 sf[4];
#pragma unroll
        for (int i = 0; i < 4; ++i) sf[i] = (f32x4){0.f, 0.f, 0.f, 0.f};
        __builtin_amdgcn_s_setprio(1);
#pragma unroll
        for (int t = 0; t < 2; ++t) {
            const int rsl = ((t * 4 + l4) ^ (l15 & 7)) << 3;
#pragma unroll
            for (int fj = 0; fj < 4; ++fj) {
                const bf16x8 kf = *(const bf16x8*)&Ks[cur][(fj * 16 + l15) * 64 + rsl];
                sf[fj] = __builtin_amdgcn_mfma_f32_16x16x32_bf16(qf[t], kf, sf[fj], 0, 0, 0);
            }
        }
        __builtin_amdgcn_s_setprio(0);
        // ---- exp + P -> LDS (swizzled) ----
#pragma unroll
        for (int fj = 0; fj < 4; ++fj)
#pragma unroll
            for (int r = 0; r < 4; ++r) {
                const float p = __expf(sf[fj][r]);
                const bf16_t pb = (bf16_t)p;
                psum[r] += (float)pb;
                const int q = l4 * 4 + r;
                const int slot = (fj * 2 + (l15 >> 3)) ^ ((q >> 1) & 7);
                Ps[w][q * 64 + slot * 8 + (l15 & 7)] = pb;
            }
        // ---- PV: O[16q x 64d] ----
        __builtin_amdgcn_s_setprio(1);
#pragma unroll
        for (int t = 0; t < 2; ++t) {
            const int pslot = ((t * 4 + l4) ^ ((l15 >> 1) & 7)) << 3;
            const bf16x8 pf = *(const bf16x8*)&Ps[w][l15 * 64 + pslot];
            const int rsl = ((t * 4 + l4) ^ (l15 & 7)) << 3;
#pragma unroll
            for (int fd = 0; fd < 4; ++fd) {
                const bf16x8 vf = *(const bf16x8*)&Vs[cur][(fd * 16 + l15) * 64 + rsl];
                of[fd] = __builtin_amdgcn_mfma_f32_16x16x32_bf16(pf, vf, of[fd], 0, 0, 0);
            }
        }
        __builtin_amdgcn_s_setprio(0);
        __syncthreads();   // next tile staged + all waves done with cur
        cur ^= 1;
    }
#undef STAGE
    // row-sum reduce across the 16 lanes sharing a row group
#pragma unroll
    for (int r = 0; r < 4; ++r)
#pragma unroll
        for (int msk = 1; msk < 16; msk <<= 1) psum[r] += __shfl_xor(psum[r], msk);
    // store O / sum
#pragma unroll
    for (int r = 0; r < 4; ++r) {
        const float inv = 1.f / psum[r];
        float* orow = att + (size_t)(b * S_ + q0 + l4 * 4 + r) * D_ + h * DH_;
#pragma unroll
        for (int fd = 0; fd < 4; ++fd) orow[fd * 16 + l15] = of[fd][r] * inv;
    }
}

// ------------- LayerNorm over D=1024, fp16 out -------------
__global__ __launch_bounds__(256)
void layernorm_k(const float* __restrict__ in, const void* __restrict__ g,
                 const void* __restrict__ be, const int* __restrict__ flag,
                 f16_t* __restrict__ x16) {
    const int row = blockIdx.x, tid = threadIdx.x;
    const int lane = tid & 63, wave = tid >> 6;
    const int f = flag[0];
    const float* r = in + (size_t)row * D_;
    float v[4], s = 0.f, ss = 0.f;
#pragma unroll
    for (int i = 0; i < 4; ++i) {
        v[i] = r[tid + i * 256];
        s += v[i]; ss += v[i] * v[i];
    }
#pragma unroll
    for (int msk = 1; msk < 64; msk <<= 1) { s += __shfl_xor(s, msk); ss += __shfl_xor(ss, msk); }
    __shared__ float rs[4], rss[4];
    if (lane == 0) { rs[wave] = s; rss[wave] = ss; }
    __syncthreads();
    s = rs[0] + rs[1] + rs[2] + rs[3];
    ss = rss[0] + rss[1] + rss[2] + rss[3];
    const float mu = s * (1.f / (float)D_);
    const float var = fmaxf(ss * (1.f / (float)D_) - mu * mu, 0.f);
    const float inv = rsqrtf(var + 1e-5f);
    f16_t* hr = x16 + (size_t)row * D_;
#pragma unroll
    for (int i = 0; i < 4; ++i) {
        const int c = tid + i * 256;
        hr[c] = (f16_t)((v[i] - mu) * inv * ldx(g, c, f) + ldx(be, c, f));
    }
}

__global__ void host_marker_k(int code, float* __restrict__ out) {
    if (code != 0) out[0] = 1e10f * (float)(1 + code);
}

extern "C" void kernel_launch(void* const* d_in, const int* in_sizes, int n_in,
                              void* d_out, int out_size, void* d_ws, size_t ws_size,
                              hipStream_t stream) {
    (void)out_size;
    const void* Q    = d_in[0];
    const void* Wqkv = d_in[3];
    const void* bqkv = d_in[4];
    const void* qsc  = d_in[5];
    const void* ksc  = d_in[6];
    const void* ln_g = d_in[7];
    const void* ln_b = d_in[8];
    const void* W1   = d_in[9];
    const void* b1   = d_in[10];
    const void* W2   = d_in[11];
    const void* b2   = d_in[12];

    // ws layout (bytes), time-multiplexed:
    //   [0,50331648)           qkv16 fp16 (gemm->qkv_post/vtrans)
    //        after vtrans:     att f32 [0,32M) + x16 fp16 [32M,48M)
    //   [50331648,83886080)    h16 fp16 (FF1->FF2)
    //   [83886080,100663296)   q16 fp16 (cvt->QKV gemm) -> Qb bf16 (qkv_post->attn)
    //   [100663296,117440512)  Kb bf16
    //   [117440512,134217728)  Vt bf16
    //   [134217728,148897792)  wq16 6M | w116 4M | w216 4M
    //   [148897792,...)        rope tables + flag
    constexpr size_t OFF_QKV16 = 0;
    constexpr size_t OFF_ATT   = 0;
    constexpr size_t OFF_X16   = 33554432;
    constexpr size_t OFF_H16   = 50331648;
    constexpr size_t OFF_Q16   = 83886080;
    constexpr size_t OFF_QB    = 83886080;
    constexpr size_t OFF_KB    = 100663296;
    constexpr size_t OFF_VT    = 117440512;
    constexpr size_t OFF_WQ16  = 134217728;
    constexpr size_t OFF_W116  = 140509184;
    constexpr size_t OFF_W216  = 144703488;
    constexpr size_t OFF_RC    = 148897792;
    constexpr size_t OFF_RS    = OFF_RC + 262144;
    constexpr size_t OFF_RSC   = OFF_RS + 262144;
    constexpr size_t OFF_FLAG  = OFF_RSC + 262144;   // 149684224
    constexpr size_t WS_NEED   = OFF_FLAG + 64;      // ~142.75 MB (proven OK)

    float* out = (float*)d_out;                      // FP32 output
    char* ws = (char*)d_ws;
    f16_t*  qkv16 = (f16_t*)(ws + OFF_QKV16);
    float*  attb  = (float*)(ws + OFF_ATT);
    f16_t*  x16   = (f16_t*)(ws + OFF_X16);
    f16_t*  h16   = (f16_t*)(ws + OFF_H16);
    f16_t*  q16   = (f16_t*)(ws + OFF_Q16);
    bf16_t* qb    = (bf16_t*)(ws + OFF_QB);
    bf16_t* kb    = (bf16_t*)(ws + OFF_KB);
    bf16_t* vtb   = (bf16_t*)(ws + OFF_VT);
    f16_t*  wq16  = (f16_t*)(ws + OFF_WQ16);
    f16_t*  w116  = (f16_t*)(ws + OFF_W116);
    f16_t*  w216  = (f16_t*)(ws + OFF_W216);
    float*  rc    = (float*)(ws + OFF_RC);
    float*  rsn   = (float*)(ws + OFF_RS);
    float*  rsc   = (float*)(ws + OFF_RSC);
    int*    flag  = (int*)(ws + OFF_FLAG);   // flag[0]=input dtype (1=fp32), flag[1]=1

    int err_stage = 0;
    (void)hipGetLastError();
    #define LCHK(stage) do { if (hipGetLastError() != hipSuccess && err_stage == 0) err_stage = (stage); } while (0)

    if (n_in != 13) err_stage = 90;
    else if (in_sizes[0] != 8388608 || in_sizes[3] != 3145728 || in_sizes[4] != 3072 ||
             in_sizes[5] != 64 || in_sizes[7] != 1024 || in_sizes[9] != 2097152 ||
             in_sizes[10] != 2048 || in_sizes[11] != 2097152 || in_sizes[12] != 1024)
        err_stage = 91;
    else if (ws_size < WS_NEED) err_stage = 92;
    if (err_stage != 0) {
        host_marker_k<<<1, 1, 0, stream>>>(err_stage, out);
        return;
    }

    detect_k<<<1, 256, 0, stream>>>((const unsigned short*)Q, 65536, flag);        LCHK(1);
    rope_tables_k<<<S_, 32, 0, stream>>>(rc, rsn, rsc);                            LCHK(2);
    // fp16 conversions / transposes
    cvt16_k<<<(M_ * D_ / 8) / 256, 256, 0, stream>>>(Q, flag, q16, M_ * D_ / 8);   LCHK(3);
    prep_wt16_k<<<dim3(3 * D_ / 32, D_ / 32), 256, 0, stream>>>(
        Wqkv, flag, wq16, D_, 3 * D_);                                             LCHK(4);
    prep_wt16_k<<<dim3(FF_ / 32, D_ / 32), 256, 0, stream>>>(
        W1, flag, w116, D_, FF_);                                                  LCHK(5);
    prep_wt16_k<<<dim3(D_ / 32, FF_ / 32), 256, 0, stream>>>(
        W2, flag, w216, FF_, D_);                                                  LCHK(6);
    // qkv16 = Q @ Wqkv + bqkv  (fp16 MFMA, fp16 out)
    gemm16_k<0, 1, 0><<<dim3(3 * D_ / 128, M_ / 128), 256, 0, stream>>>(
        q16, wq16, bqkv, flag, nullptr, nullptr, nullptr, qkv16, M_, 3 * D_, D_);  LCHK(7);
    // l2norm + scale + rope; q -> Qb bf16 (0.125-folded, overlays dead q16), k -> Kb
    qkv_post_k<<<(M_ * H_) / 256, 256, 0, stream>>>(
        qkv16, qsc, ksc, flag, rc, rsn, rsc, qb, kb);                              LCHK(8);
    // v -> Vt bf16 transposed
    vtrans_k<<<dim3(S_ / 32, H_, B_), 256, 0, stream>>>(qkv16, vtb);               LCHK(9);
    // MFMA flash attention -> att staged in ws (fp32)
    attn_mfma_k<<<B_ * H_ * (S_ / 64), 256, 0, stream>>>(qb, kb, vtb, attb);       LCHK(10);
    // LayerNorm(att) -> x16 fp16 (qkv16 region dead)
    layernorm_k<<<M_, 256, 0, stream>>>(attb, ln_g, ln_b, flag, x16);              LCHK(11);
    // h16 = silu(x @ W1 + b1)  (fp16 out)
    gemm16_k<1, 1, 0><<<dim3(FF_ / 128, M_ / 128), 256, 0, stream>>>(
        x16, w116, b1, flag, nullptr, nullptr, nullptr, h16, M_, FF_, D_);         LCHK(12);
    // out = x + h @ W2 + b2  (fp32 out, resid from x16)
    gemm16_k<0, 0, 2><<<dim3(D_ / 128, M_ / 128), 256, 0, stream>>>(
        h16, w216, b2, flag, nullptr, x16, out, nullptr, M_, D_, FF_);             LCHK(13);
    host_marker_k<<<1, 1, 0, stream>>>(err_stage, out);
    #undef LCHK
}